// Round 7
// baseline (677.014 us; speedup 1.0000x reference)
//
#include <hip/hip_runtime.h>
#include <hip/hip_bf16.h>

// TransformerBlock on MI355X (gfx950) — round 11: attn occupancy.
// Attn is latency-bound (throughput floor ~33us, measured ~85): serial phase
// chain + only 2 blocks/CU. Fix: Ps back to 64 rows (serial per-sub PV, the
// proven v4 pattern; +16 av reads/tile is cheap LDS throughput) -> LDS 50KB
// -> 3 blocks/CU, and all 512 blocks resident from t=0 (no tail).
// launch_bounds(256,3) on attn+gemm_bt (gemm_bt uses 168 regs <= 170 cap).
// GEMMs: R1-proven plateau structure (schedule ports closed after 3 fails;
// ffn's 12.6M bank conflicts are the documented 2-phase-null signature).
// Fused launches: cvt_all+rmsnorm1 -> prep_k; rope+transv -> rope_tv.
// B=4 S=2048 D=1024 H=16 DK=64 DFF=4096. fp32 in/out, bf16 tensor-core.

typedef unsigned short u16;
typedef __attribute__((ext_vector_type(8))) short short8;    // 8 bf16 (MFMA A/B frag)
typedef __attribute__((ext_vector_type(4))) float f32x4;     // 16x16 C/D frag
typedef __attribute__((ext_vector_type(16))) float f32x16;   // 32x32 C/D frag

#define MFMA16(a, b, c) __builtin_amdgcn_mfma_f32_16x16x32_bf16(a, b, c, 0, 0, 0)
#define MFMA32(a, b, c) __builtin_amdgcn_mfma_f32_32x32x16_bf16(a, b, c, 0, 0, 0)
#define VMC(N) asm volatile("s_waitcnt vmcnt(" #N ")" ::: "memory")

__device__ __forceinline__ u16 f2b(float f) {
  union { float f; unsigned u; } x; x.f = f;
  unsigned r = x.u + 0x7FFFu + ((x.u >> 16) & 1u);   // RNE
  return (u16)(r >> 16);
}
__device__ __forceinline__ float b2f(u16 h) {
  union { unsigned u; float f; } x; x.u = ((unsigned)h) << 16;
  return x.f;
}
__device__ __forceinline__ unsigned pkbf(float a, float b) {
  __hip_bfloat162 h = __float22bfloat162_rn(make_float2(a, b));
  union { __hip_bfloat162 h; unsigned u; } cv; cv.h = h;
  return cv.u;
}
// async global->LDS, 16B per lane; LDS dest = wave-uniform base + lane*16.
__device__ __forceinline__ void async16(const void* g, void* l) {
  __builtin_amdgcn_global_load_lds(
      (const __attribute__((address_space(1))) void*)g,
      (__attribute__((address_space(3))) void*)l, 16, 0, 0);
}

// ---------------------------------------------------------------------------
// GEMM (bt-form): C[m,n] = sum_k A[m,k]*B[n,k] — R1-proven structure.
// (256,3): 168 unified regs fits the 170 cap -> codegen unchanged, 3 blk/CU.
// ---------------------------------------------------------------------------
template <int MODE>
__global__ __launch_bounds__(256, 3) void gemm_bt(
    const u16* __restrict__ A, const u16* __restrict__ B,
    u16* __restrict__ Cb, float* __restrict__ Cf, const float* __restrict__ R,
    int M, int N, int K) {
  __shared__ __align__(16) u16 As[128 * 64];
  __shared__ __align__(16) u16 Bs[128 * 64];
  const int tid = threadIdx.x;
  const int l = tid & 63, w = tid >> 6;
  const int wr = w & 1, wc = w >> 1;
  const int lr = l & 31, lh = l >> 5;
  const size_t m0 = (size_t)blockIdx.y * 128, n0 = (size_t)blockIdx.x * 128;
  f32x16 acc[2][2] = {};
  for (int k0 = 0; k0 < K; k0 += 64) {
#pragma unroll
    for (int t = 0; t < 4; ++t) {
      int c = t * 256 + tid;
      int r = c >> 3;
      int gc = ((c & 7) ^ (r & 7)) << 3;
      async16(A + (m0 + r) * (size_t)K + k0 + gc, &As[c * 8]);
    }
#pragma unroll
    for (int t = 0; t < 4; ++t) {
      int c = t * 256 + tid;
      int r = c >> 3;
      int gc = ((c & 7) ^ (r & 7)) << 3;
      async16(B + (n0 + r) * (size_t)K + k0 + gc, &Bs[c * 8]);
    }
    __syncthreads();
#pragma unroll
    for (int c = 0; c < 4; ++c) {
      const int c8 = c * 2 + lh;
      short8 af[2], bfr[2];
#pragma unroll
      for (int mi = 0; mi < 2; ++mi) {
        int r = wr * 64 + mi * 32 + lr;
        af[mi] = *(const short8*)&As[r * 64 + ((c8 ^ (r & 7)) << 3)];
      }
#pragma unroll
      for (int ni = 0; ni < 2; ++ni) {
        int r = wc * 64 + ni * 32 + lr;
        bfr[ni] = *(const short8*)&Bs[r * 64 + ((c8 ^ (r & 7)) << 3)];
      }
#pragma unroll
      for (int mi = 0; mi < 2; ++mi)
#pragma unroll
        for (int ni = 0; ni < 2; ++ni)
          acc[mi][ni] = MFMA32(af[mi], bfr[ni], acc[mi][ni]);
    }
    __syncthreads();
  }
#pragma unroll
  for (int mi = 0; mi < 2; ++mi)
#pragma unroll
    for (int ni = 0; ni < 2; ++ni) {
      size_t n = n0 + wc * 64 + ni * 32 + lr;
#pragma unroll
      for (int reg = 0; reg < 16; ++reg) {
        size_t m = m0 + wr * 64 + mi * 32 + (reg & 3) + 8 * (reg >> 2) + 4 * lh;
        float v = acc[mi][ni][reg];
        if (MODE == 0)
          Cb[m * (size_t)N + n] = f2b(v);
        else
          Cf[m * (size_t)N + n] = v + R[m * (size_t)N + n];
      }
    }
}

// ---------------------------------------------------------------------------
// Fused SwiGLU GEMM — R1-proven. (232 regs -> stays (256,2).)
// ---------------------------------------------------------------------------
__global__ __launch_bounds__(256, 2) void ffn_gemm(
    const u16* __restrict__ A, const u16* __restrict__ B1,
    const u16* __restrict__ B3, u16* __restrict__ Hout, int M, int N, int K) {
  __shared__ __align__(16) u16 As[128 * 64];
  __shared__ __align__(16) u16 B1s[128 * 64];
  __shared__ __align__(16) u16 B3s[128 * 64];
  const int tid = threadIdx.x;
  const int l = tid & 63, w = tid >> 6;
  const int wr = w & 1, wc = w >> 1;
  const int lr = l & 31, lh = l >> 5;
  const size_t m0 = (size_t)blockIdx.y * 128, n0 = (size_t)blockIdx.x * 128;
  f32x16 a1[2][2] = {}, a3[2][2] = {};
  for (int k0 = 0; k0 < K; k0 += 64) {
#pragma unroll
    for (int t = 0; t < 4; ++t) {
      int c = t * 256 + tid;
      int r = c >> 3;
      int gc = ((c & 7) ^ (r & 7)) << 3;
      async16(A + (m0 + r) * (size_t)K + k0 + gc, &As[c * 8]);
      async16(B1 + (n0 + r) * (size_t)K + k0 + gc, &B1s[c * 8]);
      async16(B3 + (n0 + r) * (size_t)K + k0 + gc, &B3s[c * 8]);
    }
    __syncthreads();
#pragma unroll
    for (int c = 0; c < 4; ++c) {
      const int c8 = c * 2 + lh;
      short8 af[2], b1f[2], b3f[2];
#pragma unroll
      for (int mi = 0; mi < 2; ++mi) {
        int r = wr * 64 + mi * 32 + lr;
        af[mi] = *(const short8*)&As[r * 64 + ((c8 ^ (r & 7)) << 3)];
      }
#pragma unroll
      for (int ni = 0; ni < 2; ++ni) {
        int r = wc * 64 + ni * 32 + lr;
        b1f[ni] = *(const short8*)&B1s[r * 64 + ((c8 ^ (r & 7)) << 3)];
        b3f[ni] = *(const short8*)&B3s[r * 64 + ((c8 ^ (r & 7)) << 3)];
      }
#pragma unroll
      for (int mi = 0; mi < 2; ++mi)
#pragma unroll
        for (int ni = 0; ni < 2; ++ni) {
          a1[mi][ni] = MFMA32(af[mi], b1f[ni], a1[mi][ni]);
          a3[mi][ni] = MFMA32(af[mi], b3f[ni], a3[mi][ni]);
        }
    }
    __syncthreads();
  }
#pragma unroll
  for (int mi = 0; mi < 2; ++mi)
#pragma unroll
    for (int ni = 0; ni < 2; ++ni) {
      size_t n = n0 + wc * 64 + ni * 32 + lr;
#pragma unroll
      for (int reg = 0; reg < 16; ++reg) {
        size_t m = m0 + wr * 64 + mi * 32 + (reg & 3) + 8 * (reg >> 2) + 4 * lh;
        float u = a1[mi][ni][reg];
        float g = u / (1.0f + __expf(-u));  // silu
        Hout[m * (size_t)N + n] = f2b(g * a3[mi][ni][reg]);
      }
    }
}

// ---------------------------------------------------------------------------
// Flash attention v8 (causal): R4/R6 structure, Ps shrunk to 64 rows (serial
// per-sub P-write+PV, wave-private in-order LDS) -> LDS 50KB -> 3 blocks/CU;
// all 512 blocks resident from t=0. Softmax: 4-chain reductions + defer-max.
// ---------------------------------------------------------------------------
__global__ __launch_bounds__(256, 3) void attn_k(
    const u16* __restrict__ qh, const u16* __restrict__ kh,
    const u16* __restrict__ vt, u16* __restrict__ aout) {
  __shared__ __align__(16) u16 Ks[128 * 64];
  __shared__ __align__(16) u16 Vs[64 * 128];
  __shared__ __align__(16) u16 Ps[64 * 136];
  const int tid = threadIdx.x;
  const int l = tid & 63, w = tid >> 6;
  const int q = l & 15, lq = l >> 4;
  const int bh = blockIdx.y;
  const size_t base = (size_t)bh * (2048 * 64);
  const int b = bh >> 4, h = bh & 15;

#define STAGE_K(kvt)                                                          \
  { _Pragma("unroll") for (int t = 0; t < 4; ++t) {                           \
      int p = t * 256 + tid;                                                  \
      int r = p >> 3, cs = p & 7;                                             \
      async16(kh + base + (size_t)((kvt) * 128 + r) * 64 + ((cs ^ (r & 7)) << 3), \
              &Ks[p * 8]); } }
#define STAGE_V(kvt)                                                          \
  { _Pragma("unroll") for (int t = 0; t < 4; ++t) {                           \
      int p = t * 256 + tid;                                                  \
      int r = p >> 4, cs = p & 15;                                            \
      async16(vt + base + (size_t)r * 2048 + (kvt) * 128 + ((cs ^ (r & 15)) << 3), \
              &Vs[p * 8]); } }
#define BARRIER                                                               \
  __builtin_amdgcn_sched_barrier(0);                                          \
  __builtin_amdgcn_s_barrier();                                               \
  __builtin_amdgcn_sched_barrier(0)

#pragma unroll 1
  for (int pass = 0; pass < 2; ++pass) {
    const int qt = pass ? (int)blockIdx.x : 15 - (int)blockIdx.x;
    const int q0 = qt << 7;
    const int nt = qt + 1;
    const int qcol[2] = {q0 + w * 16 + q, q0 + 64 + w * 16 + q};
    short8 bq[2][2];
#pragma unroll
    for (int sub = 0; sub < 2; ++sub)
#pragma unroll
      for (int kk = 0; kk < 2; ++kk)
        bq[sub][kk] = *(const short8*)(qh + base + (size_t)qcol[sub] * 64 + kk * 32 + lq * 8);

    f32x4 o[2][4] = {};
    float mI[2] = {-1e30f, -1e30f}, lI[2] = {0.0f, 0.0f};
    u16* pr = &Ps[(w * 16 + q) * 136];

    BARRIER;            // WAR vs previous pass's Ks/Vs reads (pass 0: harmless)
    STAGE_K(0);
    STAGE_V(0);

#pragma unroll 1
    for (int it = 0; it < nt; ++it) {
      if (it == 0) { VMC(4); } else { VMC(0); }
      BARRIER;          // K(it) visible; prev PV done -> Vs reusable
      if (it) STAGE_V(it);

      f32x4 s[2][8] = {};
#pragma unroll
      for (int kk = 0; kk < 2; ++kk) {
#pragma unroll
        for (int mt = 0; mt < 8; ++mt) {
          int row = mt * 16 + q;
          short8 ak = *(const short8*)&Ks[row * 64 + (((kk * 4 + lq) ^ (q & 7)) << 3)];
          s[0][mt] = MFMA16(ak, bq[0][kk], s[0][mt]);
          s[1][mt] = MFMA16(ak, bq[1][kk], s[1][mt]);
        }
      }
      BARRIER;          // all waves done reading Ks -> safe to restage K
      if (it + 1 < nt) STAGE_K(it + 1);

      const bool last = (it == nt - 1);
      if (last) {  // causal mask
        const int kv0 = it << 7;
#pragma unroll
        for (int sub = 0; sub < 2; ++sub)
#pragma unroll
          for (int mt = 0; mt < 8; ++mt)
#pragma unroll
            for (int r = 0; r < 4; ++r)
              if (kv0 + mt * 16 + lq * 4 + r > qcol[sub]) s[sub][mt][r] = -1e30f;
      }
      // online softmax, exp2 domain (Q prescaled in rope_k).
#pragma unroll
      for (int sub = 0; sub < 2; ++sub) {
        // 4 parallel max-chains (depth 8), then combine
        float c0 = -1e30f, c1 = -1e30f, c2 = -1e30f, c3 = -1e30f;
#pragma unroll
        for (int mt = 0; mt < 8; ++mt) {
          c0 = fmaxf(c0, s[sub][mt][0]);
          c1 = fmaxf(c1, s[sub][mt][1]);
          c2 = fmaxf(c2, s[sub][mt][2]);
          c3 = fmaxf(c3, s[sub][mt][3]);
        }
        float mx = fmaxf(fmaxf(c0, c1), fmaxf(c2, c3));
        // T13 defer-max: if no lane's local max exceeds mI+8, keep stale max
        // (P bounded by 2^8 — safe in bf16); skip max-shfls and O-rescale.
        float mn = mI[sub];
        const bool full = !__all(mx <= mI[sub] + 8.0f);
        if (full) {
          mx = fmaxf(mx, __shfl_xor(mx, 16, 64));
          mx = fmaxf(mx, __shfl_xor(mx, 32, 64));
          mn = fmaxf(mI[sub], mx);
        }
        float t0 = 0.0f, t1 = 0.0f, t2 = 0.0f, t3 = 0.0f;
#pragma unroll
        for (int mt = 0; mt < 8; ++mt) {
          float p0 = exp2f(s[sub][mt][0] - mn);
          float p1 = exp2f(s[sub][mt][1] - mn);
          float p2 = exp2f(s[sub][mt][2] - mn);
          float p3 = exp2f(s[sub][mt][3] - mn);
          s[sub][mt][0] = p0; s[sub][mt][1] = p1;
          s[sub][mt][2] = p2; s[sub][mt][3] = p3;
          t0 += p0; t1 += p1; t2 += p2; t3 += p3;
        }
        float rs = (t0 + t1) + (t2 + t3);
        rs += __shfl_xor(rs, 16, 64);
        rs += __shfl_xor(rs, 32, 64);
        if (full) {
          const float al = exp2f(mI[sub] - mn);
          mI[sub] = mn;
          lI[sub] = lI[sub] * al + rs;
#pragma unroll
          for (int mt = 0; mt < 4; ++mt)
#pragma unroll
            for (int r = 0; r < 4; ++r) o[sub][mt][r] *= al;
        } else {
          lI[sub] += rs;
        }
      }
      if (it + 1 < nt) { VMC(4); } else { VMC(0); }
      BARRIER;          // V(it) visible
      // serial per-sub: P-write (wave-private rows, in-wave order) then PV.
#pragma unroll
      for (int sub = 0; sub < 2; ++sub) {
#pragma unroll
        for (int mt = 0; mt < 8; ++mt) {
          uint2 pd;
          pd.x = pkbf(s[sub][mt][0], s[sub][mt][1]);
          pd.y = pkbf(s[sub][mt][2], s[sub][mt][3]);
          *(uint2*)&pr[mt * 16 + lq * 4] = pd;
        }
#pragma unroll
        for (int kk = 0; kk < 4; ++kk) {
          short8 bp = *(const short8*)&pr[kk * 32 + lq * 8];
#pragma unroll
          for (int mt = 0; mt < 4; ++mt) {
            int row = mt * 16 + q;
            short8 av = *(const short8*)&Vs[row * 128 + (((kk * 4 + lq) ^ (row & 15)) << 3)];
            o[sub][mt] = MFMA16(av, bp, o[sub][mt]);
          }
        }
      }
    }
#pragma unroll
    for (int sub = 0; sub < 2; ++sub) {
      const float inv = 1.0f / lI[sub];
#pragma unroll
      for (int mt = 0; mt < 4; ++mt) {
        uint2 pd;
        pd.x = pkbf(o[sub][mt][0] * inv, o[sub][mt][1] * inv);
        pd.y = pkbf(o[sub][mt][2] * inv, o[sub][mt][3] * inv);
        *(uint2*)&aout[((size_t)(b * 2048 + qcol[sub])) * 1024 + h * 64 + mt * 16 + lq * 4] = pd;
      }
    }
  }
#undef STAGE_K
#undef STAGE_V
#undef BARRIER
}

// ---------------------------------------------------------------------------
// prep_k: fused rmsnorm(ln1) [blocks 0..8191] + weight cvt [blocks 8192..24575].
// Parallelizes the two BW-bound startup passes and saves a launch.
// ---------------------------------------------------------------------------
__global__ __launch_bounds__(256) void prep_k(
    const float* __restrict__ x, const float* __restrict__ ln1, u16* __restrict__ xout,
    const float* __restrict__ qp, const float* __restrict__ kp,
    const float* __restrict__ vp, const float* __restrict__ op,
    const float* __restrict__ w1, const float* __restrict__ w3,
    const float* __restrict__ w2,
    u16* __restrict__ WQKV, u16* __restrict__ WO,
    u16* __restrict__ W1, u16* __restrict__ W3, u16* __restrict__ W2) {
  __shared__ float red[4];
  const int bid = blockIdx.x;
  const int tid = threadIdx.x;
  if (bid < 8192) {
    const int row = bid;
    const float4 v = ((const float4*)(x + (size_t)row * 1024))[tid];
    float ss = v.x * v.x + v.y * v.y + v.z * v.z + v.w * v.w;
#pragma unroll
    for (int d = 1; d < 64; d <<= 1) ss += __shfl_xor(ss, d, 64);
    if ((tid & 63) == 0) red[tid >> 6] = ss;
    __syncthreads();
    const float sc = rsqrtf((red[0] + red[1] + red[2] + red[3]) * (1.0f / 1024.0f) + 1e-5f);
    const float4 wv = ((const float4*)ln1)[tid];
    uint2 pv;
    pv.x = pkbf(v.x * sc * wv.x, v.y * sc * wv.y);
    pv.y = pkbf(v.z * sc * wv.z, v.w * sc * wv.w);
    *(uint2*)(xout + (size_t)row * 1024 + tid * 4) = pv;
  } else {
    int i = (bid - 8192) * 256 + tid;  // [0, 4194304)
    const float* src;
    u16* dst;
    int off;
    if (i < 1048576) {
      int seg = i >> 18, within = i & 262143;
      src = (seg == 0) ? qp : (seg == 1) ? kp : (seg == 2) ? vp : op;
      dst = (seg == 3) ? WO : WQKV + (size_t)seg * 1048576;
      off = within;
    } else {
      int j = i - 1048576;
      int seg = j >> 20;
      off = j & 1048575;
      src = (seg == 0) ? w1 : (seg == 1) ? w3 : w2;
      dst = (seg == 0) ? W1 : (seg == 1) ? W3 : W2;
    }
    float4 v = ((const float4*)src)[off];
    uint2 pv;
    pv.x = pkbf(v.x, v.y);
    pv.y = pkbf(v.z, v.w);
    *(uint2*)(dst + (size_t)off * 4) = pv;
  }
}

// rmsnorm (ln2) standalone
__global__ __launch_bounds__(256) void rmsnorm_k(
    const float* __restrict__ x, const float* __restrict__ w, u16* __restrict__ out) {
  const int row = blockIdx.x;
  const int tid = threadIdx.x;
  const float4 v = ((const float4*)(x + (size_t)row * 1024))[tid];
  float ss = v.x * v.x + v.y * v.y + v.z * v.z + v.w * v.w;
#pragma unroll
  for (int d = 1; d < 64; d <<= 1) ss += __shfl_xor(ss, d, 64);
  __shared__ float red[4];
  if ((tid & 63) == 0) red[tid >> 6] = ss;
  __syncthreads();
  const float sc = rsqrtf((red[0] + red[1] + red[2] + red[3]) * (1.0f / 1024.0f) + 1e-5f);
  const float4 wv = ((const float4*)w)[tid];
  uint2 pv;
  pv.x = pkbf(v.x * sc * wv.x, v.y * sc * wv.y);
  pv.y = pkbf(v.z * sc * wv.z, v.w * sc * wv.w);
  *(uint2*)(out + (size_t)row * 1024 + tid * 4) = pv;
}

// ---------------------------------------------------------------------------
// rope_tv: fused RoPE [blocks 0..8191] + V-transpose [blocks 8192..10239].
// RoPE: QKV [8192][3072] -> QH/KH [b][h][s][64]; Q prescaled 0.125*log2(e).
// transv: cols 2048..3071 -> vT [b][h][d][s] via 64x64 LDS tile.
// ---------------------------------------------------------------------------
__global__ __launch_bounds__(256) void rope_tv(
    const u16* __restrict__ qkv, u16* __restrict__ qh, u16* __restrict__ kh,
    const int* __restrict__ pos, u16* __restrict__ vt) {
  __shared__ u16 t[64][65];
  const int bid = blockIdx.x;
  const int tid = threadIdx.x;
  if (bid < 8192) {
    int idx = bid * 256 + tid;  // 8192 rows * 256 groups
    int grp = idx & 255;
    int row = idx >> 8;
    int which = grp >> 7;  // 0=q, 1=k
    int p = grp & 127;
    int s = row & 2047, b = row >> 11;
    int h = p >> 3, gi = p & 7;
    const u16* src = qkv + (size_t)row * 3072 + which * 1024 + h * 64 + gi * 8;
    uint4 in = *(const uint4*)src;
    const u16* e = (const u16*)&in;
    const float fp = (float)pos[s];
    const float scale = which ? 1.0f : 0.18033688011112042f;  // 0.125*log2(e)
    uint4 outv;
    unsigned* ov = (unsigned*)&outv;
#pragma unroll
    for (int j = 0; j < 4; ++j) {
      int i = gi * 4 + j;  // pair index 0..31
      float xe = b2f(e[2 * j]), xo = b2f(e[2 * j + 1]);
      float inv = exp2f(-(float)(2 * i) * (13.287712379549449f / 64.0f));
      float ang = fp * inv;
      float sn, cs;
      __sincosf(ang, &sn, &cs);
      ov[j] = pkbf((xe * cs - xo * sn) * scale, (xe * sn + xo * cs) * scale);
    }
    u16* dst = (which ? kh : qh) + (((size_t)(b * 16 + h)) * 2048 + s) * 64 + gi * 8;
    *(uint4*)dst = outv;
  } else {
    const int bq = bid - 8192;
    const int s0 = (bq & 31) * 64, bh = bq >> 5;
    const int b = bh >> 4, h = bh & 15;
#pragma unroll
    for (int i = 0; i < 16; ++i) {
      int e = i * 256 + tid;
      int sl = e >> 6, d = e & 63;
      t[sl][d] = qkv[((size_t)(b * 2048 + s0 + sl)) * 3072 + 2048 + h * 64 + d];
    }
    __syncthreads();
#pragma unroll
    for (int i = 0; i < 16; ++i) {
      int e = i * 256 + tid;
      int d = e >> 6, sl = e & 63;
      vt[((size_t)(bh * 64 + d)) * 2048 + s0 + sl] = t[sl][d];
    }
  }
}

// ---------------------------------------------------------------------------
extern "C" void kernel_launch(void* const* d_in, const int* in_sizes, int n_in,
                              void* d_out, int out_size, void* d_ws, size_t ws_size,
                              hipStream_t stream) {
  const float* x   = (const float*)d_in[0];
  const int*   pos = (const int*)d_in[1];
  const float* qp  = (const float*)d_in[2];
  const float* kp  = (const float*)d_in[3];
  const float* vp  = (const float*)d_in[4];
  const float* op  = (const float*)d_in[5];
  const float* w1  = (const float*)d_in[6];
  const float* w2  = (const float*)d_in[7];   // dict order: w2 before w3
  const float* w3  = (const float*)d_in[8];
  const float* ln1 = (const float*)d_in[9];
  const float* ln2 = (const float*)d_in[10];
  float* out = (float*)d_out;
  char* ws = (char*)d_ws;
  const size_t MB = 1024 * 1024;

  u16* WQKV = (u16*)(ws + 0 * MB);    // [3072][1024] stacked q,k,v  (6 MB)
  u16* WO   = (u16*)(ws + 6 * MB);
  u16* W1   = (u16*)(ws + 8 * MB);
  u16* W3   = (u16*)(ws + 16 * MB);
  u16* W2   = (u16*)(ws + 24 * MB);
  u16* XLN  = (u16*)(ws + 32 * MB);
  u16* QKV  = (u16*)(ws + 48 * MB);   // [8192][3072]  (48..96 MB)
  u16* QH   = (u16*)(ws + 96 * MB);
  u16* KH   = (u16*)(ws + 112 * MB);
  u16* VT   = (u16*)(ws + 128 * MB);
  u16* ATT  = (u16*)(ws + 48 * MB);   // reuses QKV
  u16* XLN2 = (u16*)(ws + 64 * MB);
  u16* Hbuf = (u16*)(ws + 80 * MB);   // 64 MB (VT dead by then)
  (void)in_sizes; (void)n_in; (void)out_size; (void)ws_size;

  prep_k<<<24576, 256, 0, stream>>>(x, ln1, XLN, qp, kp, vp, op, w1, w3, w2,
                                    WQKV, WO, W1, W3, W2);
  gemm_bt<0><<<dim3(24, 64), 256, 0, stream>>>(XLN, WQKV, QKV, nullptr, nullptr, 8192, 3072, 1024);
  rope_tv<<<10240, 256, 0, stream>>>(QKV, QH, KH, pos, VT);
  attn_k<<<dim3(8, 64), 256, 0, stream>>>(QH, KH, VT, ATT);
  gemm_bt<1><<<dim3(8, 64), 256, 0, stream>>>(ATT, WO, nullptr, out, x, 8192, 1024, 1024);
  rmsnorm_k<<<8192, 256, 0, stream>>>(out, ln2, XLN2);
  ffn_gemm<<<dim3(32, 64), 256, 0, stream>>>(XLN2, W1, W3, Hbuf, 8192, 4096, 1024);
  gemm_bt<1><<<dim3(8, 64), 256, 0, stream>>>(Hbuf, W2, nullptr, out, out, 8192, 1024, 4096);
}

// Round 8
// 598.312 us; speedup vs baseline: 1.1315x; 1.1315x over previous
//
#include <hip/hip_runtime.h>
#include <hip/hip_bf16.h>

// TransformerBlock on MI355X (gfx950) — round 12: revert the (256,3) caps.
// R7's __launch_bounds__(256,3) forced scratch spills (attn VGPR 104->84,
// WRITE_SIZE 16->102MB, +190MB HBM round-trip, attn 85->167us). The Ps=64
// LDS shrink (50KB) is KEPT: with (256,2) the natural ~104-VGPR allocation
// is LDS-limited to 3 blocks/CU — occupancy goal achieved without spills.
// GEMMs at the R1-proven plateau structure with (256,2). prep_k/rope_tv
// launch fusions kept. Softmax diet (defer-max + parallel chains) kept.
// B=4 S=2048 D=1024 H=16 DK=64 DFF=4096. fp32 in/out, bf16 tensor-core.

typedef unsigned short u16;
typedef __attribute__((ext_vector_type(8))) short short8;    // 8 bf16 (MFMA A/B frag)
typedef __attribute__((ext_vector_type(4))) float f32x4;     // 16x16 C/D frag
typedef __attribute__((ext_vector_type(16))) float f32x16;   // 32x32 C/D frag

#define MFMA16(a, b, c) __builtin_amdgcn_mfma_f32_16x16x32_bf16(a, b, c, 0, 0, 0)
#define MFMA32(a, b, c) __builtin_amdgcn_mfma_f32_32x32x16_bf16(a, b, c, 0, 0, 0)
#define VMC(N) asm volatile("s_waitcnt vmcnt(" #N ")" ::: "memory")

__device__ __forceinline__ u16 f2b(float f) {
  union { float f; unsigned u; } x; x.f = f;
  unsigned r = x.u + 0x7FFFu + ((x.u >> 16) & 1u);   // RNE
  return (u16)(r >> 16);
}
__device__ __forceinline__ float b2f(u16 h) {
  union { unsigned u; float f; } x; x.u = ((unsigned)h) << 16;
  return x.f;
}
__device__ __forceinline__ unsigned pkbf(float a, float b) {
  __hip_bfloat162 h = __float22bfloat162_rn(make_float2(a, b));
  union { __hip_bfloat162 h; unsigned u; } cv; cv.h = h;
  return cv.u;
}
// async global->LDS, 16B per lane; LDS dest = wave-uniform base + lane*16.
__device__ __forceinline__ void async16(const void* g, void* l) {
  __builtin_amdgcn_global_load_lds(
      (const __attribute__((address_space(1))) void*)g,
      (__attribute__((address_space(3))) void*)l, 16, 0, 0);
}

// ---------------------------------------------------------------------------
// GEMM (bt-form): C[m,n] = sum_k A[m,k]*B[n,k] — R1-proven structure.
// ---------------------------------------------------------------------------
template <int MODE>
__global__ __launch_bounds__(256, 2) void gemm_bt(
    const u16* __restrict__ A, const u16* __restrict__ B,
    u16* __restrict__ Cb, float* __restrict__ Cf, const float* __restrict__ R,
    int M, int N, int K) {
  __shared__ __align__(16) u16 As[128 * 64];
  __shared__ __align__(16) u16 Bs[128 * 64];
  const int tid = threadIdx.x;
  const int l = tid & 63, w = tid >> 6;
  const int wr = w & 1, wc = w >> 1;
  const int lr = l & 31, lh = l >> 5;
  const size_t m0 = (size_t)blockIdx.y * 128, n0 = (size_t)blockIdx.x * 128;
  f32x16 acc[2][2] = {};
  for (int k0 = 0; k0 < K; k0 += 64) {
#pragma unroll
    for (int t = 0; t < 4; ++t) {
      int c = t * 256 + tid;
      int r = c >> 3;
      int gc = ((c & 7) ^ (r & 7)) << 3;
      async16(A + (m0 + r) * (size_t)K + k0 + gc, &As[c * 8]);
    }
#pragma unroll
    for (int t = 0; t < 4; ++t) {
      int c = t * 256 + tid;
      int r = c >> 3;
      int gc = ((c & 7) ^ (r & 7)) << 3;
      async16(B + (n0 + r) * (size_t)K + k0 + gc, &Bs[c * 8]);
    }
    __syncthreads();
#pragma unroll
    for (int c = 0; c < 4; ++c) {
      const int c8 = c * 2 + lh;
      short8 af[2], bfr[2];
#pragma unroll
      for (int mi = 0; mi < 2; ++mi) {
        int r = wr * 64 + mi * 32 + lr;
        af[mi] = *(const short8*)&As[r * 64 + ((c8 ^ (r & 7)) << 3)];
      }
#pragma unroll
      for (int ni = 0; ni < 2; ++ni) {
        int r = wc * 64 + ni * 32 + lr;
        bfr[ni] = *(const short8*)&Bs[r * 64 + ((c8 ^ (r & 7)) << 3)];
      }
#pragma unroll
      for (int mi = 0; mi < 2; ++mi)
#pragma unroll
        for (int ni = 0; ni < 2; ++ni)
          acc[mi][ni] = MFMA32(af[mi], bfr[ni], acc[mi][ni]);
    }
    __syncthreads();
  }
#pragma unroll
  for (int mi = 0; mi < 2; ++mi)
#pragma unroll
    for (int ni = 0; ni < 2; ++ni) {
      size_t n = n0 + wc * 64 + ni * 32 + lr;
#pragma unroll
      for (int reg = 0; reg < 16; ++reg) {
        size_t m = m0 + wr * 64 + mi * 32 + (reg & 3) + 8 * (reg >> 2) + 4 * lh;
        float v = acc[mi][ni][reg];
        if (MODE == 0)
          Cb[m * (size_t)N + n] = f2b(v);
        else
          Cf[m * (size_t)N + n] = v + R[m * (size_t)N + n];
      }
    }
}

// ---------------------------------------------------------------------------
// Fused SwiGLU GEMM — R1-proven.
// ---------------------------------------------------------------------------
__global__ __launch_bounds__(256, 2) void ffn_gemm(
    const u16* __restrict__ A, const u16* __restrict__ B1,
    const u16* __restrict__ B3, u16* __restrict__ Hout, int M, int N, int K) {
  __shared__ __align__(16) u16 As[128 * 64];
  __shared__ __align__(16) u16 B1s[128 * 64];
  __shared__ __align__(16) u16 B3s[128 * 64];
  const int tid = threadIdx.x;
  const int l = tid & 63, w = tid >> 6;
  const int wr = w & 1, wc = w >> 1;
  const int lr = l & 31, lh = l >> 5;
  const size_t m0 = (size_t)blockIdx.y * 128, n0 = (size_t)blockIdx.x * 128;
  f32x16 a1[2][2] = {}, a3[2][2] = {};
  for (int k0 = 0; k0 < K; k0 += 64) {
#pragma unroll
    for (int t = 0; t < 4; ++t) {
      int c = t * 256 + tid;
      int r = c >> 3;
      int gc = ((c & 7) ^ (r & 7)) << 3;
      async16(A + (m0 + r) * (size_t)K + k0 + gc, &As[c * 8]);
      async16(B1 + (n0 + r) * (size_t)K + k0 + gc, &B1s[c * 8]);
      async16(B3 + (n0 + r) * (size_t)K + k0 + gc, &B3s[c * 8]);
    }
    __syncthreads();
#pragma unroll
    for (int c = 0; c < 4; ++c) {
      const int c8 = c * 2 + lh;
      short8 af[2], b1f[2], b3f[2];
#pragma unroll
      for (int mi = 0; mi < 2; ++mi) {
        int r = wr * 64 + mi * 32 + lr;
        af[mi] = *(const short8*)&As[r * 64 + ((c8 ^ (r & 7)) << 3)];
      }
#pragma unroll
      for (int ni = 0; ni < 2; ++ni) {
        int r = wc * 64 + ni * 32 + lr;
        b1f[ni] = *(const short8*)&B1s[r * 64 + ((c8 ^ (r & 7)) << 3)];
        b3f[ni] = *(const short8*)&B3s[r * 64 + ((c8 ^ (r & 7)) << 3)];
      }
#pragma unroll
      for (int mi = 0; mi < 2; ++mi)
#pragma unroll
        for (int ni = 0; ni < 2; ++ni) {
          a1[mi][ni] = MFMA32(af[mi], b1f[ni], a1[mi][ni]);
          a3[mi][ni] = MFMA32(af[mi], b3f[ni], a3[mi][ni]);
        }
    }
    __syncthreads();
  }
#pragma unroll
  for (int mi = 0; mi < 2; ++mi)
#pragma unroll
    for (int ni = 0; ni < 2; ++ni) {
      size_t n = n0 + wc * 64 + ni * 32 + lr;
#pragma unroll
      for (int reg = 0; reg < 16; ++reg) {
        size_t m = m0 + wr * 64 + mi * 32 + (reg & 3) + 8 * (reg >> 2) + 4 * lh;
        float u = a1[mi][ni][reg];
        float g = u / (1.0f + __expf(-u));  // silu
        Hout[m * (size_t)N + n] = f2b(g * a3[mi][ni][reg]);
      }
    }
}

// ---------------------------------------------------------------------------
// Flash attention v9 (causal): R4 structure, Ps=64 rows (serial per-sub PV)
// -> LDS 50KB. (256,2): no register cap -> no spills; natural ~104 VGPR is
// LDS-limited to 3 blocks/CU. Softmax: parallel chains + defer-max.
// ---------------------------------------------------------------------------
__global__ __launch_bounds__(256, 2) void attn_k(
    const u16* __restrict__ qh, const u16* __restrict__ kh,
    const u16* __restrict__ vt, u16* __restrict__ aout) {
  __shared__ __align__(16) u16 Ks[128 * 64];
  __shared__ __align__(16) u16 Vs[64 * 128];
  __shared__ __align__(16) u16 Ps[64 * 136];
  const int tid = threadIdx.x;
  const int l = tid & 63, w = tid >> 6;
  const int q = l & 15, lq = l >> 4;
  const int bh = blockIdx.y;
  const size_t base = (size_t)bh * (2048 * 64);
  const int b = bh >> 4, h = bh & 15;

#define STAGE_K(kvt)                                                          \
  { _Pragma("unroll") for (int t = 0; t < 4; ++t) {                           \
      int p = t * 256 + tid;                                                  \
      int r = p >> 3, cs = p & 7;                                             \
      async16(kh + base + (size_t)((kvt) * 128 + r) * 64 + ((cs ^ (r & 7)) << 3), \
              &Ks[p * 8]); } }
#define STAGE_V(kvt)                                                          \
  { _Pragma("unroll") for (int t = 0; t < 4; ++t) {                           \
      int p = t * 256 + tid;                                                  \
      int r = p >> 4, cs = p & 15;                                            \
      async16(vt + base + (size_t)r * 2048 + (kvt) * 128 + ((cs ^ (r & 15)) << 3), \
              &Vs[p * 8]); } }
#define BARRIER                                                               \
  __builtin_amdgcn_sched_barrier(0);                                          \
  __builtin_amdgcn_s_barrier();                                               \
  __builtin_amdgcn_sched_barrier(0)

#pragma unroll 1
  for (int pass = 0; pass < 2; ++pass) {
    const int qt = pass ? (int)blockIdx.x : 15 - (int)blockIdx.x;
    const int q0 = qt << 7;
    const int nt = qt + 1;
    const int qcol[2] = {q0 + w * 16 + q, q0 + 64 + w * 16 + q};
    short8 bq[2][2];
#pragma unroll
    for (int sub = 0; sub < 2; ++sub)
#pragma unroll
      for (int kk = 0; kk < 2; ++kk)
        bq[sub][kk] = *(const short8*)(qh + base + (size_t)qcol[sub] * 64 + kk * 32 + lq * 8);

    f32x4 o[2][4] = {};
    float mI[2] = {-1e30f, -1e30f}, lI[2] = {0.0f, 0.0f};
    u16* pr = &Ps[(w * 16 + q) * 136];

    BARRIER;            // WAR vs previous pass's Ks/Vs reads (pass 0: harmless)
    STAGE_K(0);
    STAGE_V(0);

#pragma unroll 1
    for (int it = 0; it < nt; ++it) {
      if (it == 0) { VMC(4); } else { VMC(0); }
      BARRIER;          // K(it) visible; prev PV done -> Vs reusable
      if (it) STAGE_V(it);

      f32x4 s[2][8] = {};
#pragma unroll
      for (int kk = 0; kk < 2; ++kk) {
#pragma unroll
        for (int mt = 0; mt < 8; ++mt) {
          int row = mt * 16 + q;
          short8 ak = *(const short8*)&Ks[row * 64 + (((kk * 4 + lq) ^ (q & 7)) << 3)];
          s[0][mt] = MFMA16(ak, bq[0][kk], s[0][mt]);
          s[1][mt] = MFMA16(ak, bq[1][kk], s[1][mt]);
        }
      }
      BARRIER;          // all waves done reading Ks -> safe to restage K
      if (it + 1 < nt) STAGE_K(it + 1);

      const bool last = (it == nt - 1);
      if (last) {  // causal mask
        const int kv0 = it << 7;
#pragma unroll
        for (int sub = 0; sub < 2; ++sub)
#pragma unroll
          for (int mt = 0; mt < 8; ++mt)
#pragma unroll
            for (int r = 0; r < 4; ++r)
              if (kv0 + mt * 16 + lq * 4 + r > qcol[sub]) s[sub][mt][r] = -1e30f;
      }
      // online softmax, exp2 domain (Q prescaled in rope_k).
#pragma unroll
      for (int sub = 0; sub < 2; ++sub) {
        // 4 parallel max-chains (depth 8), then combine
        float c0 = -1e30f, c1 = -1e30f, c2 = -1e30f, c3 = -1e30f;
#pragma unroll
        for (int mt = 0; mt < 8; ++mt) {
          c0 = fmaxf(c0, s[sub][mt][0]);
          c1 = fmaxf(c1, s[sub][mt][1]);
          c2 = fmaxf(c2, s[sub][mt][2]);
          c3 = fmaxf(c3, s[sub][mt][3]);
        }
        float mx = fmaxf(fmaxf(c0, c1), fmaxf(c2, c3));
        // T13 defer-max: if no lane's local max exceeds mI+8, keep stale max
        // (P bounded by 2^8 — safe in bf16); skip max-shfls and O-rescale.
        float mn = mI[sub];
        const bool full = !__all(mx <= mI[sub] + 8.0f);
        if (full) {
          mx = fmaxf(mx, __shfl_xor(mx, 16, 64));
          mx = fmaxf(mx, __shfl_xor(mx, 32, 64));
          mn = fmaxf(mI[sub], mx);
        }
        float t0 = 0.0f, t1 = 0.0f, t2 = 0.0f, t3 = 0.0f;
#pragma unroll
        for (int mt = 0; mt < 8; ++mt) {
          float p0 = exp2f(s[sub][mt][0] - mn);
          float p1 = exp2f(s[sub][mt][1] - mn);
          float p2 = exp2f(s[sub][mt][2] - mn);
          float p3 = exp2f(s[sub][mt][3] - mn);
          s[sub][mt][0] = p0; s[sub][mt][1] = p1;
          s[sub][mt][2] = p2; s[sub][mt][3] = p3;
          t0 += p0; t1 += p1; t2 += p2; t3 += p3;
        }
        float rs = (t0 + t1) + (t2 + t3);
        rs += __shfl_xor(rs, 16, 64);
        rs += __shfl_xor(rs, 32, 64);
        if (full) {
          const float al = exp2f(mI[sub] - mn);
          mI[sub] = mn;
          lI[sub] = lI[sub] * al + rs;
#pragma unroll
          for (int mt = 0; mt < 4; ++mt)
#pragma unroll
            for (int r = 0; r < 4; ++r) o[sub][mt][r] *= al;
        } else {
          lI[sub] += rs;
        }
      }
      if (it + 1 < nt) { VMC(4); } else { VMC(0); }
      BARRIER;          // V(it) visible
      // serial per-sub: P-write (wave-private rows, in-wave order) then PV.
#pragma unroll
      for (int sub = 0; sub < 2; ++sub) {
#pragma unroll
        for (int mt = 0; mt < 8; ++mt) {
          uint2 pd;
          pd.x = pkbf(s[sub][mt][0], s[sub][mt][1]);
          pd.y = pkbf(s[sub][mt][2], s[sub][mt][3]);
          *(uint2*)&pr[mt * 16 + lq * 4] = pd;
        }
#pragma unroll
        for (int kk = 0; kk < 4; ++kk) {
          short8 bp = *(const short8*)&pr[kk * 32 + lq * 8];
#pragma unroll
          for (int mt = 0; mt < 4; ++mt) {
            int row = mt * 16 + q;
            short8 av = *(const short8*)&Vs[row * 128 + (((kk * 4 + lq) ^ (row & 15)) << 3)];
            o[sub][mt] = MFMA16(av, bp, o[sub][mt]);
          }
        }
      }
    }
#pragma unroll
    for (int sub = 0; sub < 2; ++sub) {
      const float inv = 1.0f / lI[sub];
#pragma unroll
      for (int mt = 0; mt < 4; ++mt) {
        uint2 pd;
        pd.x = pkbf(o[sub][mt][0] * inv, o[sub][mt][1] * inv);
        pd.y = pkbf(o[sub][mt][2] * inv, o[sub][mt][3] * inv);
        *(uint2*)&aout[((size_t)(b * 2048 + qcol[sub])) * 1024 + h * 64 + mt * 16 + lq * 4] = pd;
      }
    }
  }
#undef STAGE_K
#undef STAGE_V
#undef BARRIER
}

// ---------------------------------------------------------------------------
// prep_k: fused rmsnorm(ln1) [blocks 0..8191] + weight cvt [blocks 8192..24575].
// ---------------------------------------------------------------------------
__global__ __launch_bounds__(256) void prep_k(
    const float* __restrict__ x, const float* __restrict__ ln1, u16* __restrict__ xout,
    const float* __restrict__ qp, const float* __restrict__ kp,
    const float* __restrict__ vp, const float* __restrict__ op,
    const float* __restrict__ w1, const float* __restrict__ w3,
    const float* __restrict__ w2,
    u16* __restrict__ WQKV, u16* __restrict__ WO,
    u16* __restrict__ W1, u16* __restrict__ W3, u16* __restrict__ W2) {
  __shared__ float red[4];
  const int bid = blockIdx.x;
  const int tid = threadIdx.x;
  if (bid < 8192) {
    const int row = bid;
    const float4 v = ((const float4*)(x + (size_t)row * 1024))[tid];
    float ss = v.x * v.x + v.y * v.y + v.z * v.z + v.w * v.w;
#pragma unroll
    for (int d = 1; d < 64; d <<= 1) ss += __shfl_xor(ss, d, 64);
    if ((tid & 63) == 0) red[tid >> 6] = ss;
    __syncthreads();
    const float sc = rsqrtf((red[0] + red[1] + red[2] + red[3]) * (1.0f / 1024.0f) + 1e-5f);
    const float4 wv = ((const float4*)ln1)[tid];
    uint2 pv;
    pv.x = pkbf(v.x * sc * wv.x, v.y * sc * wv.y);
    pv.y = pkbf(v.z * sc * wv.z, v.w * sc * wv.w);
    *(uint2*)(xout + (size_t)row * 1024 + tid * 4) = pv;
  } else {
    int i = (bid - 8192) * 256 + tid;  // [0, 4194304)
    const float* src;
    u16* dst;
    int off;
    if (i < 1048576) {
      int seg = i >> 18, within = i & 262143;
      src = (seg == 0) ? qp : (seg == 1) ? kp : (seg == 2) ? vp : op;
      dst = (seg == 3) ? WO : WQKV + (size_t)seg * 1048576;
      off = within;
    } else {
      int j = i - 1048576;
      int seg = j >> 20;
      off = j & 1048575;
      src = (seg == 0) ? w1 : (seg == 1) ? w3 : w2;
      dst = (seg == 0) ? W1 : (seg == 1) ? W3 : W2;
    }
    float4 v = ((const float4*)src)[off];
    uint2 pv;
    pv.x = pkbf(v.x, v.y);
    pv.y = pkbf(v.z, v.w);
    *(uint2*)(dst + (size_t)off * 4) = pv;
  }
}

// rmsnorm (ln2) standalone
__global__ __launch_bounds__(256) void rmsnorm_k(
    const float* __restrict__ x, const float* __restrict__ w, u16* __restrict__ out) {
  const int row = blockIdx.x;
  const int tid = threadIdx.x;
  const float4 v = ((const float4*)(x + (size_t)row * 1024))[tid];
  float ss = v.x * v.x + v.y * v.y + v.z * v.z + v.w * v.w;
#pragma unroll
  for (int d = 1; d < 64; d <<= 1) ss += __shfl_xor(ss, d, 64);
  __shared__ float red[4];
  if ((tid & 63) == 0) red[tid >> 6] = ss;
  __syncthreads();
  const float sc = rsqrtf((red[0] + red[1] + red[2] + red[3]) * (1.0f / 1024.0f) + 1e-5f);
  const float4 wv = ((const float4*)w)[tid];
  uint2 pv;
  pv.x = pkbf(v.x * sc * wv.x, v.y * sc * wv.y);
  pv.y = pkbf(v.z * sc * wv.z, v.w * sc * wv.w);
  *(uint2*)(out + (size_t)row * 1024 + tid * 4) = pv;
}

// ---------------------------------------------------------------------------
// rope_tv: fused RoPE [blocks 0..8191] + V-transpose [blocks 8192..10239].
// ---------------------------------------------------------------------------
__global__ __launch_bounds__(256) void rope_tv(
    const u16* __restrict__ qkv, u16* __restrict__ qh, u16* __restrict__ kh,
    const int* __restrict__ pos, u16* __restrict__ vt) {
  __shared__ u16 t[64][65];
  const int bid = blockIdx.x;
  const int tid = threadIdx.x;
  if (bid < 8192) {
    int idx = bid * 256 + tid;  // 8192 rows * 256 groups
    int grp = idx & 255;
    int row = idx >> 8;
    int which = grp >> 7;  // 0=q, 1=k
    int p = grp & 127;
    int s = row & 2047, b = row >> 11;
    int h = p >> 3, gi = p & 7;
    const u16* src = qkv + (size_t)row * 3072 + which * 1024 + h * 64 + gi * 8;
    uint4 in = *(const uint4*)src;
    const u16* e = (const u16*)&in;
    const float fp = (float)pos[s];
    const float scale = which ? 1.0f : 0.18033688011112042f;  // 0.125*log2(e)
    uint4 outv;
    unsigned* ov = (unsigned*)&outv;
#pragma unroll
    for (int j = 0; j < 4; ++j) {
      int i = gi * 4 + j;  // pair index 0..31
      float xe = b2f(e[2 * j]), xo = b2f(e[2 * j + 1]);
      float inv = exp2f(-(float)(2 * i) * (13.287712379549449f / 64.0f));
      float ang = fp * inv;
      float sn, cs;
      __sincosf(ang, &sn, &cs);
      ov[j] = pkbf((xe * cs - xo * sn) * scale, (xe * sn + xo * cs) * scale);
    }
    u16* dst = (which ? kh : qh) + (((size_t)(b * 16 + h)) * 2048 + s) * 64 + gi * 8;
    *(uint4*)dst = outv;
  } else {
    const int bq = bid - 8192;
    const int s0 = (bq & 31) * 64, bh = bq >> 5;
    const int b = bh >> 4, h = bh & 15;
#pragma unroll
    for (int i = 0; i < 16; ++i) {
      int e = i * 256 + tid;
      int sl = e >> 6, d = e & 63;
      t[sl][d] = qkv[((size_t)(b * 2048 + s0 + sl)) * 3072 + 2048 + h * 64 + d];
    }
    __syncthreads();
#pragma unroll
    for (int i = 0; i < 16; ++i) {
      int e = i * 256 + tid;
      int d = e >> 6, sl = e & 63;
      vt[((size_t)(bh * 64 + d)) * 2048 + s0 + sl] = t[sl][d];
    }
  }
}

// ---------------------------------------------------------------------------
extern "C" void kernel_launch(void* const* d_in, const int* in_sizes, int n_in,
                              void* d_out, int out_size, void* d_ws, size_t ws_size,
                              hipStream_t stream) {
  const float* x   = (const float*)d_in[0];
  const int*   pos = (const int*)d_in[1];
  const float* qp  = (const float*)d_in[2];
  const float* kp  = (const float*)d_in[3];
  const float* vp  = (const float*)d_in[4];
  const float* op  = (const float*)d_in[5];
  const float* w1  = (const float*)d_in[6];
  const float* w2  = (const float*)d_in[7];   // dict order: w2 before w3
  const float* w3  = (const float*)d_in[8];
  const float* ln1 = (const float*)d_in[9];
  const float* ln2 = (const float*)d_in[10];
  float* out = (float*)d_out;
  char* ws = (char*)d_ws;
  const size_t MB = 1024 * 1024;

  u16* WQKV = (u16*)(ws + 0 * MB);    // [3072][1024] stacked q,k,v  (6 MB)
  u16* WO   = (u16*)(ws + 6 * MB);
  u16* W1   = (u16*)(ws + 8 * MB);
  u16* W3   = (u16*)(ws + 16 * MB);
  u16* W2   = (u16*)(ws + 24 * MB);
  u16* XLN  = (u16*)(ws + 32 * MB);
  u16* QKV  = (u16*)(ws + 48 * MB);   // [8192][3072]  (48..96 MB)
  u16* QH   = (u16*)(ws + 96 * MB);
  u16* KH   = (u16*)(ws + 112 * MB);
  u16* VT   = (u16*)(ws + 128 * MB);
  u16* ATT  = (u16*)(ws + 48 * MB);   // reuses QKV
  u16* XLN2 = (u16*)(ws + 64 * MB);
  u16* Hbuf = (u16*)(ws + 80 * MB);   // 64 MB (VT dead by then)
  (void)in_sizes; (void)n_in; (void)out_size; (void)ws_size;

  prep_k<<<24576, 256, 0, stream>>>(x, ln1, XLN, qp, kp, vp, op, w1, w3, w2,
                                    WQKV, WO, W1, W3, W2);
  gemm_bt<0><<<dim3(24, 64), 256, 0, stream>>>(XLN, WQKV, QKV, nullptr, nullptr, 8192, 3072, 1024);
  rope_tv<<<10240, 256, 0, stream>>>(QKV, QH, KH, pos, VT);
  attn_k<<<dim3(8, 64), 256, 0, stream>>>(QH, KH, VT, ATT);
  gemm_bt<1><<<dim3(8, 64), 256, 0, stream>>>(ATT, WO, nullptr, out, x, 8192, 1024, 1024);
  rmsnorm_k<<<8192, 256, 0, stream>>>(out, ln2, XLN2);
  ffn_gemm<<<dim3(32, 64), 256, 0, stream>>>(XLN2, W1, W3, Hbuf, 8192, 4096, 1024);
  gemm_bt<1><<<dim3(8, 64), 256, 0, stream>>>(Hbuf, W2, nullptr, out, out, 8192, 1024, 4096);
}

// Round 9
// 586.345 us; speedup vs baseline: 1.1546x; 1.0204x over previous
//
#include <hip/hip_runtime.h>
#include <hip/hip_bf16.h>

// TransformerBlock on MI355X (gfx950) — round 13: measured-best assembly.
// R8's serial-per-sub PV regressed ~40us (serial P-write->PV->P-write LDS
// chain + lost shared-av reads; 3blk/CU didn't cover it). Revert attn to the
// R6-proven v7: Ps=128 (pr0/pr1), fused PV (one av read feeds both subs),
// defer-max diet. Add T5 setprio(1) around attn MFMA clusters (+4-7% attn,
// m191-proven for independent-block attn). GEMMs: R1 plateau structure.
// prep_k/rope_tv launch fusions kept. No __launch_bounds__ register caps
// beyond (256,2) — R7 proved (256,3) spills.
// B=4 S=2048 D=1024 H=16 DK=64 DFF=4096. fp32 in/out, bf16 tensor-core.

typedef unsigned short u16;
typedef __attribute__((ext_vector_type(8))) short short8;    // 8 bf16 (MFMA A/B frag)
typedef __attribute__((ext_vector_type(4))) float f32x4;     // 16x16 C/D frag
typedef __attribute__((ext_vector_type(16))) float f32x16;   // 32x32 C/D frag

#define MFMA16(a, b, c) __builtin_amdgcn_mfma_f32_16x16x32_bf16(a, b, c, 0, 0, 0)
#define MFMA32(a, b, c) __builtin_amdgcn_mfma_f32_32x32x16_bf16(a, b, c, 0, 0, 0)
#define VMC(N) asm volatile("s_waitcnt vmcnt(" #N ")" ::: "memory")

__device__ __forceinline__ u16 f2b(float f) {
  union { float f; unsigned u; } x; x.f = f;
  unsigned r = x.u + 0x7FFFu + ((x.u >> 16) & 1u);   // RNE
  return (u16)(r >> 16);
}
__device__ __forceinline__ float b2f(u16 h) {
  union { unsigned u; float f; } x; x.u = ((unsigned)h) << 16;
  return x.f;
}
__device__ __forceinline__ unsigned pkbf(float a, float b) {
  __hip_bfloat162 h = __float22bfloat162_rn(make_float2(a, b));
  union { __hip_bfloat162 h; unsigned u; } cv; cv.h = h;
  return cv.u;
}
// async global->LDS, 16B per lane; LDS dest = wave-uniform base + lane*16.
__device__ __forceinline__ void async16(const void* g, void* l) {
  __builtin_amdgcn_global_load_lds(
      (const __attribute__((address_space(1))) void*)g,
      (__attribute__((address_space(3))) void*)l, 16, 0, 0);
}

// ---------------------------------------------------------------------------
// GEMM (bt-form): C[m,n] = sum_k A[m,k]*B[n,k] — R1-proven structure.
// ---------------------------------------------------------------------------
template <int MODE>
__global__ __launch_bounds__(256, 2) void gemm_bt(
    const u16* __restrict__ A, const u16* __restrict__ B,
    u16* __restrict__ Cb, float* __restrict__ Cf, const float* __restrict__ R,
    int M, int N, int K) {
  __shared__ __align__(16) u16 As[128 * 64];
  __shared__ __align__(16) u16 Bs[128 * 64];
  const int tid = threadIdx.x;
  const int l = tid & 63, w = tid >> 6;
  const int wr = w & 1, wc = w >> 1;
  const int lr = l & 31, lh = l >> 5;
  const size_t m0 = (size_t)blockIdx.y * 128, n0 = (size_t)blockIdx.x * 128;
  f32x16 acc[2][2] = {};
  for (int k0 = 0; k0 < K; k0 += 64) {
#pragma unroll
    for (int t = 0; t < 4; ++t) {
      int c = t * 256 + tid;
      int r = c >> 3;
      int gc = ((c & 7) ^ (r & 7)) << 3;
      async16(A + (m0 + r) * (size_t)K + k0 + gc, &As[c * 8]);
    }
#pragma unroll
    for (int t = 0; t < 4; ++t) {
      int c = t * 256 + tid;
      int r = c >> 3;
      int gc = ((c & 7) ^ (r & 7)) << 3;
      async16(B + (n0 + r) * (size_t)K + k0 + gc, &Bs[c * 8]);
    }
    __syncthreads();
#pragma unroll
    for (int c = 0; c < 4; ++c) {
      const int c8 = c * 2 + lh;
      short8 af[2], bfr[2];
#pragma unroll
      for (int mi = 0; mi < 2; ++mi) {
        int r = wr * 64 + mi * 32 + lr;
        af[mi] = *(const short8*)&As[r * 64 + ((c8 ^ (r & 7)) << 3)];
      }
#pragma unroll
      for (int ni = 0; ni < 2; ++ni) {
        int r = wc * 64 + ni * 32 + lr;
        bfr[ni] = *(const short8*)&Bs[r * 64 + ((c8 ^ (r & 7)) << 3)];
      }
#pragma unroll
      for (int mi = 0; mi < 2; ++mi)
#pragma unroll
        for (int ni = 0; ni < 2; ++ni)
          acc[mi][ni] = MFMA32(af[mi], bfr[ni], acc[mi][ni]);
    }
    __syncthreads();
  }
#pragma unroll
  for (int mi = 0; mi < 2; ++mi)
#pragma unroll
    for (int ni = 0; ni < 2; ++ni) {
      size_t n = n0 + wc * 64 + ni * 32 + lr;
#pragma unroll
      for (int reg = 0; reg < 16; ++reg) {
        size_t m = m0 + wr * 64 + mi * 32 + (reg & 3) + 8 * (reg >> 2) + 4 * lh;
        float v = acc[mi][ni][reg];
        if (MODE == 0)
          Cb[m * (size_t)N + n] = f2b(v);
        else
          Cf[m * (size_t)N + n] = v + R[m * (size_t)N + n];
      }
    }
}

// ---------------------------------------------------------------------------
// Fused SwiGLU GEMM — R1-proven.
// ---------------------------------------------------------------------------
__global__ __launch_bounds__(256, 2) void ffn_gemm(
    const u16* __restrict__ A, const u16* __restrict__ B1,
    const u16* __restrict__ B3, u16* __restrict__ Hout, int M, int N, int K) {
  __shared__ __align__(16) u16 As[128 * 64];
  __shared__ __align__(16) u16 B1s[128 * 64];
  __shared__ __align__(16) u16 B3s[128 * 64];
  const int tid = threadIdx.x;
  const int l = tid & 63, w = tid >> 6;
  const int wr = w & 1, wc = w >> 1;
  const int lr = l & 31, lh = l >> 5;
  const size_t m0 = (size_t)blockIdx.y * 128, n0 = (size_t)blockIdx.x * 128;
  f32x16 a1[2][2] = {}, a3[2][2] = {};
  for (int k0 = 0; k0 < K; k0 += 64) {
#pragma unroll
    for (int t = 0; t < 4; ++t) {
      int c = t * 256 + tid;
      int r = c >> 3;
      int gc = ((c & 7) ^ (r & 7)) << 3;
      async16(A + (m0 + r) * (size_t)K + k0 + gc, &As[c * 8]);
      async16(B1 + (n0 + r) * (size_t)K + k0 + gc, &B1s[c * 8]);
      async16(B3 + (n0 + r) * (size_t)K + k0 + gc, &B3s[c * 8]);
    }
    __syncthreads();
#pragma unroll
    for (int c = 0; c < 4; ++c) {
      const int c8 = c * 2 + lh;
      short8 af[2], b1f[2], b3f[2];
#pragma unroll
      for (int mi = 0; mi < 2; ++mi) {
        int r = wr * 64 + mi * 32 + lr;
        af[mi] = *(const short8*)&As[r * 64 + ((c8 ^ (r & 7)) << 3)];
      }
#pragma unroll
      for (int ni = 0; ni < 2; ++ni) {
        int r = wc * 64 + ni * 32 + lr;
        b1f[ni] = *(const short8*)&B1s[r * 64 + ((c8 ^ (r & 7)) << 3)];
        b3f[ni] = *(const short8*)&B3s[r * 64 + ((c8 ^ (r & 7)) << 3)];
      }
#pragma unroll
      for (int mi = 0; mi < 2; ++mi)
#pragma unroll
        for (int ni = 0; ni < 2; ++ni) {
          a1[mi][ni] = MFMA32(af[mi], b1f[ni], a1[mi][ni]);
          a3[mi][ni] = MFMA32(af[mi], b3f[ni], a3[mi][ni]);
        }
    }
    __syncthreads();
  }
#pragma unroll
  for (int mi = 0; mi < 2; ++mi)
#pragma unroll
    for (int ni = 0; ni < 2; ++ni) {
      size_t n = n0 + wc * 64 + ni * 32 + lr;
#pragma unroll
      for (int reg = 0; reg < 16; ++reg) {
        size_t m = m0 + wr * 64 + mi * 32 + (reg & 3) + 8 * (reg >> 2) + 4 * lh;
        float u = a1[mi][ni][reg];
        float g = u / (1.0f + __expf(-u));  // silu
        Hout[m * (size_t)N + n] = f2b(g * a3[mi][ni][reg]);
      }
    }
}

// ---------------------------------------------------------------------------
// Flash attention v10 (causal): R6-proven v7 structure (Ps=128, fused PV
// sharing av reads, paired q-tiles, split K/V staging, defer-max diet)
// + T5 setprio around MFMA clusters. LDS 66KB -> 2 blocks/CU.
// ---------------------------------------------------------------------------
__global__ __launch_bounds__(256, 2) void attn_k(
    const u16* __restrict__ qh, const u16* __restrict__ kh,
    const u16* __restrict__ vt, u16* __restrict__ aout) {
  __shared__ __align__(16) u16 Ks[128 * 64];
  __shared__ __align__(16) u16 Vs[64 * 128];
  __shared__ __align__(16) u16 Ps[128 * 136];
  const int tid = threadIdx.x;
  const int l = tid & 63, w = tid >> 6;
  const int q = l & 15, lq = l >> 4;
  const int bh = blockIdx.y;
  const size_t base = (size_t)bh * (2048 * 64);
  const int b = bh >> 4, h = bh & 15;

#define STAGE_K(kvt)                                                          \
  { _Pragma("unroll") for (int t = 0; t < 4; ++t) {                           \
      int p = t * 256 + tid;                                                  \
      int r = p >> 3, cs = p & 7;                                             \
      async16(kh + base + (size_t)((kvt) * 128 + r) * 64 + ((cs ^ (r & 7)) << 3), \
              &Ks[p * 8]); } }
#define STAGE_V(kvt)                                                          \
  { _Pragma("unroll") for (int t = 0; t < 4; ++t) {                           \
      int p = t * 256 + tid;                                                  \
      int r = p >> 4, cs = p & 15;                                            \
      async16(vt + base + (size_t)r * 2048 + (kvt) * 128 + ((cs ^ (r & 15)) << 3), \
              &Vs[p * 8]); } }
#define BARRIER                                                               \
  __builtin_amdgcn_sched_barrier(0);                                          \
  __builtin_amdgcn_s_barrier();                                               \
  __builtin_amdgcn_sched_barrier(0)

#pragma unroll 1
  for (int pass = 0; pass < 2; ++pass) {
    const int qt = pass ? (int)blockIdx.x : 15 - (int)blockIdx.x;
    const int q0 = qt << 7;
    const int nt = qt + 1;
    const int qcol[2] = {q0 + w * 16 + q, q0 + 64 + w * 16 + q};
    short8 bq[2][2];
#pragma unroll
    for (int sub = 0; sub < 2; ++sub)
#pragma unroll
      for (int kk = 0; kk < 2; ++kk)
        bq[sub][kk] = *(const short8*)(qh + base + (size_t)qcol[sub] * 64 + kk * 32 + lq * 8);

    f32x4 o[2][4] = {};
    float mI[2] = {-1e30f, -1e30f}, lI[2] = {0.0f, 0.0f};
    u16* pr0 = &Ps[(w * 16 + q) * 136];
    u16* pr1 = &Ps[(64 + w * 16 + q) * 136];

    BARRIER;            // WAR vs previous pass's Ks/Vs reads (pass 0: harmless)
    STAGE_K(0);
    STAGE_V(0);

#pragma unroll 1
    for (int it = 0; it < nt; ++it) {
      if (it == 0) { VMC(4); } else { VMC(0); }
      BARRIER;          // K(it) visible; prev PV done -> Vs reusable
      if (it) STAGE_V(it);

      f32x4 s[2][8] = {};
      __builtin_amdgcn_s_setprio(1);
#pragma unroll
      for (int kk = 0; kk < 2; ++kk) {
#pragma unroll
        for (int mt = 0; mt < 8; ++mt) {
          int row = mt * 16 + q;
          short8 ak = *(const short8*)&Ks[row * 64 + (((kk * 4 + lq) ^ (q & 7)) << 3)];
          s[0][mt] = MFMA16(ak, bq[0][kk], s[0][mt]);
          s[1][mt] = MFMA16(ak, bq[1][kk], s[1][mt]);
        }
      }
      __builtin_amdgcn_s_setprio(0);
      BARRIER;          // all waves done reading Ks -> safe to restage K
      if (it + 1 < nt) STAGE_K(it + 1);

      const bool last = (it == nt - 1);
      if (last) {  // causal mask
        const int kv0 = it << 7;
#pragma unroll
        for (int sub = 0; sub < 2; ++sub)
#pragma unroll
          for (int mt = 0; mt < 8; ++mt)
#pragma unroll
            for (int r = 0; r < 4; ++r)
              if (kv0 + mt * 16 + lq * 4 + r > qcol[sub]) s[sub][mt][r] = -1e30f;
      }
      // online softmax, exp2 domain (Q prescaled in rope_k).
#pragma unroll
      for (int sub = 0; sub < 2; ++sub) {
        // 4 parallel max-chains (depth 8), then combine
        float c0 = -1e30f, c1 = -1e30f, c2 = -1e30f, c3 = -1e30f;
#pragma unroll
        for (int mt = 0; mt < 8; ++mt) {
          c0 = fmaxf(c0, s[sub][mt][0]);
          c1 = fmaxf(c1, s[sub][mt][1]);
          c2 = fmaxf(c2, s[sub][mt][2]);
          c3 = fmaxf(c3, s[sub][mt][3]);
        }
        float mx = fmaxf(fmaxf(c0, c1), fmaxf(c2, c3));
        // T13 defer-max: if no lane's local max exceeds mI+8, keep stale max
        // (P bounded by 2^8 — safe in bf16); skip max-shfls and O-rescale.
        float mn = mI[sub];
        const bool full = !__all(mx <= mI[sub] + 8.0f);
        if (full) {
          mx = fmaxf(mx, __shfl_xor(mx, 16, 64));
          mx = fmaxf(mx, __shfl_xor(mx, 32, 64));
          mn = fmaxf(mI[sub], mx);
        }
        float t0 = 0.0f, t1 = 0.0f, t2 = 0.0f, t3 = 0.0f;
#pragma unroll
        for (int mt = 0; mt < 8; ++mt) {
          float p0 = exp2f(s[sub][mt][0] - mn);
          float p1 = exp2f(s[sub][mt][1] - mn);
          float p2 = exp2f(s[sub][mt][2] - mn);
          float p3 = exp2f(s[sub][mt][3] - mn);
          s[sub][mt][0] = p0; s[sub][mt][1] = p1;
          s[sub][mt][2] = p2; s[sub][mt][3] = p3;
          t0 += p0; t1 += p1; t2 += p2; t3 += p3;
        }
        float rs = (t0 + t1) + (t2 + t3);
        rs += __shfl_xor(rs, 16, 64);
        rs += __shfl_xor(rs, 32, 64);
        if (full) {
          const float al = exp2f(mI[sub] - mn);
          mI[sub] = mn;
          lI[sub] = lI[sub] * al + rs;
#pragma unroll
          for (int mt = 0; mt < 4; ++mt)
#pragma unroll
            for (int r = 0; r < 4; ++r) o[sub][mt][r] *= al;
        } else {
          lI[sub] += rs;
        }
        // P^T -> Ps (wave-private rows; separate row-sets per sub)
        u16* pr = sub ? pr1 : pr0;
#pragma unroll
        for (int mt = 0; mt < 8; ++mt) {
          uint2 pd;
          pd.x = pkbf(s[sub][mt][0], s[sub][mt][1]);
          pd.y = pkbf(s[sub][mt][2], s[sub][mt][3]);
          *(uint2*)&pr[mt * 16 + lq * 4] = pd;
        }
      }
      if (it + 1 < nt) { VMC(4); } else { VMC(0); }
      BARRIER;          // V(it) visible
      // fused PV: one av read feeds BOTH subtiles.
      __builtin_amdgcn_s_setprio(1);
#pragma unroll
      for (int kk = 0; kk < 4; ++kk) {
        short8 bp0 = *(const short8*)&pr0[kk * 32 + lq * 8];
        short8 bp1 = *(const short8*)&pr1[kk * 32 + lq * 8];
#pragma unroll
        for (int mt = 0; mt < 4; ++mt) {
          int row = mt * 16 + q;
          short8 av = *(const short8*)&Vs[row * 128 + (((kk * 4 + lq) ^ (row & 15)) << 3)];
          o[0][mt] = MFMA16(av, bp0, o[0][mt]);
          o[1][mt] = MFMA16(av, bp1, o[1][mt]);
        }
      }
      __builtin_amdgcn_s_setprio(0);
    }
#pragma unroll
    for (int sub = 0; sub < 2; ++sub) {
      const float inv = 1.0f / lI[sub];
#pragma unroll
      for (int mt = 0; mt < 4; ++mt) {
        uint2 pd;
        pd.x = pkbf(o[sub][mt][0] * inv, o[sub][mt][1] * inv);
        pd.y = pkbf(o[sub][mt][2] * inv, o[sub][mt][3] * inv);
        *(uint2*)&aout[((size_t)(b * 2048 + qcol[sub])) * 1024 + h * 64 + mt * 16 + lq * 4] = pd;
      }
    }
  }
#undef STAGE_K
#undef STAGE_V
#undef BARRIER
}

// ---------------------------------------------------------------------------
// prep_k: fused rmsnorm(ln1) [blocks 0..8191] + weight cvt [blocks 8192..24575].
// ---------------------------------------------------------------------------
__global__ __launch_bounds__(256) void prep_k(
    const float* __restrict__ x, const float* __restrict__ ln1, u16* __restrict__ xout,
    const float* __restrict__ qp, const float* __restrict__ kp,
    const float* __restrict__ vp, const float* __restrict__ op,
    const float* __restrict__ w1, const float* __restrict__ w3,
    const float* __restrict__ w2,
    u16* __restrict__ WQKV, u16* __restrict__ WO,
    u16* __restrict__ W1, u16* __restrict__ W3, u16* __restrict__ W2) {
  __shared__ float red[4];
  const int bid = blockIdx.x;
  const int tid = threadIdx.x;
  if (bid < 8192) {
    const int row = bid;
    const float4 v = ((const float4*)(x + (size_t)row * 1024))[tid];
    float ss = v.x * v.x + v.y * v.y + v.z * v.z + v.w * v.w;
#pragma unroll
    for (int d = 1; d < 64; d <<= 1) ss += __shfl_xor(ss, d, 64);
    if ((tid & 63) == 0) red[tid >> 6] = ss;
    __syncthreads();
    const float sc = rsqrtf((red[0] + red[1] + red[2] + red[3]) * (1.0f / 1024.0f) + 1e-5f);
    const float4 wv = ((const float4*)ln1)[tid];
    uint2 pv;
    pv.x = pkbf(v.x * sc * wv.x, v.y * sc * wv.y);
    pv.y = pkbf(v.z * sc * wv.z, v.w * sc * wv.w);
    *(uint2*)(xout + (size_t)row * 1024 + tid * 4) = pv;
  } else {
    int i = (bid - 8192) * 256 + tid;  // [0, 4194304)
    const float* src;
    u16* dst;
    int off;
    if (i < 1048576) {
      int seg = i >> 18, within = i & 262143;
      src = (seg == 0) ? qp : (seg == 1) ? kp : (seg == 2) ? vp : op;
      dst = (seg == 3) ? WO : WQKV + (size_t)seg * 1048576;
      off = within;
    } else {
      int j = i - 1048576;
      int seg = j >> 20;
      off = j & 1048575;
      src = (seg == 0) ? w1 : (seg == 1) ? w3 : w2;
      dst = (seg == 0) ? W1 : (seg == 1) ? W3 : W2;
    }
    float4 v = ((const float4*)src)[off];
    uint2 pv;
    pv.x = pkbf(v.x, v.y);
    pv.y = pkbf(v.z, v.w);
    *(uint2*)(dst + (size_t)off * 4) = pv;
  }
}

// rmsnorm (ln2) standalone
__global__ __launch_bounds__(256) void rmsnorm_k(
    const float* __restrict__ x, const float* __restrict__ w, u16* __restrict__ out) {
  const int row = blockIdx.x;
  const int tid = threadIdx.x;
  const float4 v = ((const float4*)(x + (size_t)row * 1024))[tid];
  float ss = v.x * v.x + v.y * v.y + v.z * v.z + v.w * v.w;
#pragma unroll
  for (int d = 1; d < 64; d <<= 1) ss += __shfl_xor(ss, d, 64);
  __shared__ float red[4];
  if ((tid & 63) == 0) red[tid >> 6] = ss;
  __syncthreads();
  const float sc = rsqrtf((red[0] + red[1] + red[2] + red[3]) * (1.0f / 1024.0f) + 1e-5f);
  const float4 wv = ((const float4*)w)[tid];
  uint2 pv;
  pv.x = pkbf(v.x * sc * wv.x, v.y * sc * wv.y);
  pv.y = pkbf(v.z * sc * wv.z, v.w * sc * wv.w);
  *(uint2*)(out + (size_t)row * 1024 + tid * 4) = pv;
}

// ---------------------------------------------------------------------------
// rope_tv: fused RoPE [blocks 0..8191] + V-transpose [blocks 8192..10239].
// ---------------------------------------------------------------------------
__global__ __launch_bounds__(256) void rope_tv(
    const u16* __restrict__ qkv, u16* __restrict__ qh, u16* __restrict__ kh,
    const int* __restrict__ pos, u16* __restrict__ vt) {
  __shared__ u16 t[64][65];
  const int bid = blockIdx.x;
  const int tid = threadIdx.x;
  if (bid < 8192) {
    int idx = bid * 256 + tid;  // 8192 rows * 256 groups
    int grp = idx & 255;
    int row = idx >> 8;
    int which = grp >> 7;  // 0=q, 1=k
    int p = grp & 127;
    int s = row & 2047, b = row >> 11;
    int h = p >> 3, gi = p & 7;
    const u16* src = qkv + (size_t)row * 3072 + which * 1024 + h * 64 + gi * 8;
    uint4 in = *(const uint4*)src;
    const u16* e = (const u16*)&in;
    const float fp = (float)pos[s];
    const float scale = which ? 1.0f : 0.18033688011112042f;  // 0.125*log2(e)
    uint4 outv;
    unsigned* ov = (unsigned*)&outv;
#pragma unroll
    for (int j = 0; j < 4; ++j) {
      int i = gi * 4 + j;  // pair index 0..31
      float xe = b2f(e[2 * j]), xo = b2f(e[2 * j + 1]);
      float inv = exp2f(-(float)(2 * i) * (13.287712379549449f / 64.0f));
      float ang = fp * inv;
      float sn, cs;
      __sincosf(ang, &sn, &cs);
      ov[j] = pkbf((xe * cs - xo * sn) * scale, (xe * sn + xo * cs) * scale);
    }
    u16* dst = (which ? kh : qh) + (((size_t)(b * 16 + h)) * 2048 + s) * 64 + gi * 8;
    *(uint4*)dst = outv;
  } else {
    const int bq = bid - 8192;
    const int s0 = (bq & 31) * 64, bh = bq >> 5;
    const int b = bh >> 4, h = bh & 15;
#pragma unroll
    for (int i = 0; i < 16; ++i) {
      int e = i * 256 + tid;
      int sl = e >> 6, d = e & 63;
      t[sl][d] = qkv[((size_t)(b * 2048 + s0 + sl)) * 3072 + 2048 + h * 64 + d];
    }
    __syncthreads();
#pragma unroll
    for (int i = 0; i < 16; ++i) {
      int e = i * 256 + tid;
      int d = e >> 6, sl = e & 63;
      vt[((size_t)(bh * 64 + d)) * 2048 + s0 + sl] = t[sl][d];
    }
  }
}

// ---------------------------------------------------------------------------
extern "C" void kernel_launch(void* const* d_in, const int* in_sizes, int n_in,
                              void* d_out, int out_size, void* d_ws, size_t ws_size,
                              hipStream_t stream) {
  const float* x   = (const float*)d_in[0];
  const int*   pos = (const int*)d_in[1];
  const float* qp  = (const float*)d_in[2];
  const float* kp  = (const float*)d_in[3];
  const float* vp  = (const float*)d_in[4];
  const float* op  = (const float*)d_in[5];
  const float* w1  = (const float*)d_in[6];
  const float* w2  = (const float*)d_in[7];   // dict order: w2 before w3
  const float* w3  = (const float*)d_in[8];
  const float* ln1 = (const float*)d_in[9];
  const float* ln2 = (const float*)d_in[10];
  float* out = (float*)d_out;
  char* ws = (char*)d_ws;
  const size_t MB = 1024 * 1024;

  u16* WQKV = (u16*)(ws + 0 * MB);    // [3072][1024] stacked q,k,v  (6 MB)
  u16* WO   = (u16*)(ws + 6 * MB);
  u16* W1   = (u16*)(ws + 8 * MB);
  u16* W3   = (u16*)(ws + 16 * MB);
  u16* W2   = (u16*)(ws + 24 * MB);
  u16* XLN  = (u16*)(ws + 32 * MB);
  u16* QKV  = (u16*)(ws + 48 * MB);   // [8192][3072]  (48..96 MB)
  u16* QH   = (u16*)(ws + 96 * MB);
  u16* KH   = (u16*)(ws + 112 * MB);
  u16* VT   = (u16*)(ws + 128 * MB);
  u16* ATT  = (u16*)(ws + 48 * MB);   // reuses QKV
  u16* XLN2 = (u16*)(ws + 64 * MB);
  u16* Hbuf = (u16*)(ws + 80 * MB);   // 64 MB (VT dead by then)
  (void)in_sizes; (void)n_in; (void)out_size; (void)ws_size;

  prep_k<<<24576, 256, 0, stream>>>(x, ln1, XLN, qp, kp, vp, op, w1, w3, w2,
                                    WQKV, WO, W1, W3, W2);
  gemm_bt<0><<<dim3(24, 64), 256, 0, stream>>>(XLN, WQKV, QKV, nullptr, nullptr, 8192, 3072, 1024);
  rope_tv<<<10240, 256, 0, stream>>>(QKV, QH, KH, pos, VT);
  attn_k<<<dim3(8, 64), 256, 0, stream>>>(QH, KH, VT, ATT);
  gemm_bt<1><<<dim3(8, 64), 256, 0, stream>>>(ATT, WO, nullptr, out, x, 8192, 1024, 1024);
  rmsnorm_k<<<8192, 256, 0, stream>>>(out, ln2, XLN2);
  ffn_gemm<<<dim3(32, 64), 256, 0, stream>>>(XLN2, W1, W3, Hbuf, 8192, 4096, 1024);
  gemm_bt<1><<<dim3(8, 64), 256, 0, stream>>>(Hbuf, W2, nullptr, out, out, 8192, 1024, 4096);
}

// Round 10
// 558.665 us; speedup vs baseline: 1.2118x; 1.0495x over previous
//
#include <hip/hip_runtime.h>
#include <hip/hip_bf16.h>

// TransformerBlock on MI355X (gfx950) — round 14: R9 minus attn setprio.
// R9 (586us fast-clock) vs R4 (576 same clock) isolated T5 setprio as the
// regression: our attn is 4-wave barrier-lockstep — m190's NEGATIVE regime
// (setprio helps only independent-phase waves, m191). Removed. Everything
// else is the measured-best assembly: R1-plateau GEMMs (875 TF), attn v7
// (Ps=128, fused PV sharing av reads, paired q-tiles, split K/V staging,
// defer-max diet), uint2-packed stores, prep_k/rope_tv launch fusions,
// no register caps beyond (256,2) (R7 proved (256,3) spills).
// B=4 S=2048 D=1024 H=16 DK=64 DFF=4096. fp32 in/out, bf16 tensor-core.

typedef unsigned short u16;
typedef __attribute__((ext_vector_type(8))) short short8;    // 8 bf16 (MFMA A/B frag)
typedef __attribute__((ext_vector_type(4))) float f32x4;     // 16x16 C/D frag
typedef __attribute__((ext_vector_type(16))) float f32x16;   // 32x32 C/D frag

#define MFMA16(a, b, c) __builtin_amdgcn_mfma_f32_16x16x32_bf16(a, b, c, 0, 0, 0)
#define MFMA32(a, b, c) __builtin_amdgcn_mfma_f32_32x32x16_bf16(a, b, c, 0, 0, 0)
#define VMC(N) asm volatile("s_waitcnt vmcnt(" #N ")" ::: "memory")

__device__ __forceinline__ u16 f2b(float f) {
  union { float f; unsigned u; } x; x.f = f;
  unsigned r = x.u + 0x7FFFu + ((x.u >> 16) & 1u);   // RNE
  return (u16)(r >> 16);
}
__device__ __forceinline__ float b2f(u16 h) {
  union { unsigned u; float f; } x; x.u = ((unsigned)h) << 16;
  return x.f;
}
__device__ __forceinline__ unsigned pkbf(float a, float b) {
  __hip_bfloat162 h = __float22bfloat162_rn(make_float2(a, b));
  union { __hip_bfloat162 h; unsigned u; } cv; cv.h = h;
  return cv.u;
}
// async global->LDS, 16B per lane; LDS dest = wave-uniform base + lane*16.
__device__ __forceinline__ void async16(const void* g, void* l) {
  __builtin_amdgcn_global_load_lds(
      (const __attribute__((address_space(1))) void*)g,
      (__attribute__((address_space(3))) void*)l, 16, 0, 0);
}

// ---------------------------------------------------------------------------
// GEMM (bt-form): C[m,n] = sum_k A[m,k]*B[n,k] — R1-proven structure.
// ---------------------------------------------------------------------------
template <int MODE>
__global__ __launch_bounds__(256, 2) void gemm_bt(
    const u16* __restrict__ A, const u16* __restrict__ B,
    u16* __restrict__ Cb, float* __restrict__ Cf, const float* __restrict__ R,
    int M, int N, int K) {
  __shared__ __align__(16) u16 As[128 * 64];
  __shared__ __align__(16) u16 Bs[128 * 64];
  const int tid = threadIdx.x;
  const int l = tid & 63, w = tid >> 6;
  const int wr = w & 1, wc = w >> 1;
  const int lr = l & 31, lh = l >> 5;
  const size_t m0 = (size_t)blockIdx.y * 128, n0 = (size_t)blockIdx.x * 128;
  f32x16 acc[2][2] = {};
  for (int k0 = 0; k0 < K; k0 += 64) {
#pragma unroll
    for (int t = 0; t < 4; ++t) {
      int c = t * 256 + tid;
      int r = c >> 3;
      int gc = ((c & 7) ^ (r & 7)) << 3;
      async16(A + (m0 + r) * (size_t)K + k0 + gc, &As[c * 8]);
    }
#pragma unroll
    for (int t = 0; t < 4; ++t) {
      int c = t * 256 + tid;
      int r = c >> 3;
      int gc = ((c & 7) ^ (r & 7)) << 3;
      async16(B + (n0 + r) * (size_t)K + k0 + gc, &Bs[c * 8]);
    }
    __syncthreads();
#pragma unroll
    for (int c = 0; c < 4; ++c) {
      const int c8 = c * 2 + lh;
      short8 af[2], bfr[2];
#pragma unroll
      for (int mi = 0; mi < 2; ++mi) {
        int r = wr * 64 + mi * 32 + lr;
        af[mi] = *(const short8*)&As[r * 64 + ((c8 ^ (r & 7)) << 3)];
      }
#pragma unroll
      for (int ni = 0; ni < 2; ++ni) {
        int r = wc * 64 + ni * 32 + lr;
        bfr[ni] = *(const short8*)&Bs[r * 64 + ((c8 ^ (r & 7)) << 3)];
      }
#pragma unroll
      for (int mi = 0; mi < 2; ++mi)
#pragma unroll
        for (int ni = 0; ni < 2; ++ni)
          acc[mi][ni] = MFMA32(af[mi], bfr[ni], acc[mi][ni]);
    }
    __syncthreads();
  }
#pragma unroll
  for (int mi = 0; mi < 2; ++mi)
#pragma unroll
    for (int ni = 0; ni < 2; ++ni) {
      size_t n = n0 + wc * 64 + ni * 32 + lr;
#pragma unroll
      for (int reg = 0; reg < 16; ++reg) {
        size_t m = m0 + wr * 64 + mi * 32 + (reg & 3) + 8 * (reg >> 2) + 4 * lh;
        float v = acc[mi][ni][reg];
        if (MODE == 0)
          Cb[m * (size_t)N + n] = f2b(v);
        else
          Cf[m * (size_t)N + n] = v + R[m * (size_t)N + n];
      }
    }
}

// ---------------------------------------------------------------------------
// Fused SwiGLU GEMM — R1-proven.
// ---------------------------------------------------------------------------
__global__ __launch_bounds__(256, 2) void ffn_gemm(
    const u16* __restrict__ A, const u16* __restrict__ B1,
    const u16* __restrict__ B3, u16* __restrict__ Hout, int M, int N, int K) {
  __shared__ __align__(16) u16 As[128 * 64];
  __shared__ __align__(16) u16 B1s[128 * 64];
  __shared__ __align__(16) u16 B3s[128 * 64];
  const int tid = threadIdx.x;
  const int l = tid & 63, w = tid >> 6;
  const int wr = w & 1, wc = w >> 1;
  const int lr = l & 31, lh = l >> 5;
  const size_t m0 = (size_t)blockIdx.y * 128, n0 = (size_t)blockIdx.x * 128;
  f32x16 a1[2][2] = {}, a3[2][2] = {};
  for (int k0 = 0; k0 < K; k0 += 64) {
#pragma unroll
    for (int t = 0; t < 4; ++t) {
      int c = t * 256 + tid;
      int r = c >> 3;
      int gc = ((c & 7) ^ (r & 7)) << 3;
      async16(A + (m0 + r) * (size_t)K + k0 + gc, &As[c * 8]);
      async16(B1 + (n0 + r) * (size_t)K + k0 + gc, &B1s[c * 8]);
      async16(B3 + (n0 + r) * (size_t)K + k0 + gc, &B3s[c * 8]);
    }
    __syncthreads();
#pragma unroll
    for (int c = 0; c < 4; ++c) {
      const int c8 = c * 2 + lh;
      short8 af[2], b1f[2], b3f[2];
#pragma unroll
      for (int mi = 0; mi < 2; ++mi) {
        int r = wr * 64 + mi * 32 + lr;
        af[mi] = *(const short8*)&As[r * 64 + ((c8 ^ (r & 7)) << 3)];
      }
#pragma unroll
      for (int ni = 0; ni < 2; ++ni) {
        int r = wc * 64 + ni * 32 + lr;
        b1f[ni] = *(const short8*)&B1s[r * 64 + ((c8 ^ (r & 7)) << 3)];
        b3f[ni] = *(const short8*)&B3s[r * 64 + ((c8 ^ (r & 7)) << 3)];
      }
#pragma unroll
      for (int mi = 0; mi < 2; ++mi)
#pragma unroll
        for (int ni = 0; ni < 2; ++ni) {
          a1[mi][ni] = MFMA32(af[mi], b1f[ni], a1[mi][ni]);
          a3[mi][ni] = MFMA32(af[mi], b3f[ni], a3[mi][ni]);
        }
    }
    __syncthreads();
  }
#pragma unroll
  for (int mi = 0; mi < 2; ++mi)
#pragma unroll
    for (int ni = 0; ni < 2; ++ni) {
      size_t n = n0 + wc * 64 + ni * 32 + lr;
#pragma unroll
      for (int reg = 0; reg < 16; ++reg) {
        size_t m = m0 + wr * 64 + mi * 32 + (reg & 3) + 8 * (reg >> 2) + 4 * lh;
        float u = a1[mi][ni][reg];
        float g = u / (1.0f + __expf(-u));  // silu
        Hout[m * (size_t)N + n] = f2b(g * a3[mi][ni][reg]);
      }
    }
}

// ---------------------------------------------------------------------------
// Flash attention v11 (causal): v7 structure — Ps=128 (pr0/pr1), fused PV
// (one av read feeds both subtiles), paired q-tiles {15-x, x}, split K/V
// staging with counted vmcnt, defer-max diet. NO setprio (lockstep-negative).
// LDS 66KB -> 2 blocks/CU.
// ---------------------------------------------------------------------------
__global__ __launch_bounds__(256, 2) void attn_k(
    const u16* __restrict__ qh, const u16* __restrict__ kh,
    const u16* __restrict__ vt, u16* __restrict__ aout) {
  __shared__ __align__(16) u16 Ks[128 * 64];
  __shared__ __align__(16) u16 Vs[64 * 128];
  __shared__ __align__(16) u16 Ps[128 * 136];
  const int tid = threadIdx.x;
  const int l = tid & 63, w = tid >> 6;
  const int q = l & 15, lq = l >> 4;
  const int bh = blockIdx.y;
  const size_t base = (size_t)bh * (2048 * 64);
  const int b = bh >> 4, h = bh & 15;

#define STAGE_K(kvt)                                                          \
  { _Pragma("unroll") for (int t = 0; t < 4; ++t) {                           \
      int p = t * 256 + tid;                                                  \
      int r = p >> 3, cs = p & 7;                                             \
      async16(kh + base + (size_t)((kvt) * 128 + r) * 64 + ((cs ^ (r & 7)) << 3), \
              &Ks[p * 8]); } }
#define STAGE_V(kvt)                                                          \
  { _Pragma("unroll") for (int t = 0; t < 4; ++t) {                           \
      int p = t * 256 + tid;                                                  \
      int r = p >> 4, cs = p & 15;                                            \
      async16(vt + base + (size_t)r * 2048 + (kvt) * 128 + ((cs ^ (r & 15)) << 3), \
              &Vs[p * 8]); } }
#define BARRIER                                                               \
  __builtin_amdgcn_sched_barrier(0);                                          \
  __builtin_amdgcn_s_barrier();                                               \
  __builtin_amdgcn_sched_barrier(0)

#pragma unroll 1
  for (int pass = 0; pass < 2; ++pass) {
    const int qt = pass ? (int)blockIdx.x : 15 - (int)blockIdx.x;
    const int q0 = qt << 7;
    const int nt = qt + 1;
    const int qcol[2] = {q0 + w * 16 + q, q0 + 64 + w * 16 + q};
    short8 bq[2][2];
#pragma unroll
    for (int sub = 0; sub < 2; ++sub)
#pragma unroll
      for (int kk = 0; kk < 2; ++kk)
        bq[sub][kk] = *(const short8*)(qh + base + (size_t)qcol[sub] * 64 + kk * 32 + lq * 8);

    f32x4 o[2][4] = {};
    float mI[2] = {-1e30f, -1e30f}, lI[2] = {0.0f, 0.0f};
    u16* pr0 = &Ps[(w * 16 + q) * 136];
    u16* pr1 = &Ps[(64 + w * 16 + q) * 136];

    BARRIER;            // WAR vs previous pass's Ks/Vs reads (pass 0: harmless)
    STAGE_K(0);
    STAGE_V(0);

#pragma unroll 1
    for (int it = 0; it < nt; ++it) {
      if (it == 0) { VMC(4); } else { VMC(0); }
      BARRIER;          // K(it) visible; prev PV done -> Vs reusable
      if (it) STAGE_V(it);

      f32x4 s[2][8] = {};
#pragma unroll
      for (int kk = 0; kk < 2; ++kk) {
#pragma unroll
        for (int mt = 0; mt < 8; ++mt) {
          int row = mt * 16 + q;
          short8 ak = *(const short8*)&Ks[row * 64 + (((kk * 4 + lq) ^ (q & 7)) << 3)];
          s[0][mt] = MFMA16(ak, bq[0][kk], s[0][mt]);
          s[1][mt] = MFMA16(ak, bq[1][kk], s[1][mt]);
        }
      }
      BARRIER;          // all waves done reading Ks -> safe to restage K
      if (it + 1 < nt) STAGE_K(it + 1);

      const bool last = (it == nt - 1);
      if (last) {  // causal mask
        const int kv0 = it << 7;
#pragma unroll
        for (int sub = 0; sub < 2; ++sub)
#pragma unroll
          for (int mt = 0; mt < 8; ++mt)
#pragma unroll
            for (int r = 0; r < 4; ++r)
              if (kv0 + mt * 16 + lq * 4 + r > qcol[sub]) s[sub][mt][r] = -1e30f;
      }
      // online softmax, exp2 domain (Q prescaled in rope_k).
#pragma unroll
      for (int sub = 0; sub < 2; ++sub) {
        // 4 parallel max-chains (depth 8), then combine
        float c0 = -1e30f, c1 = -1e30f, c2 = -1e30f, c3 = -1e30f;
#pragma unroll
        for (int mt = 0; mt < 8; ++mt) {
          c0 = fmaxf(c0, s[sub][mt][0]);
          c1 = fmaxf(c1, s[sub][mt][1]);
          c2 = fmaxf(c2, s[sub][mt][2]);
          c3 = fmaxf(c3, s[sub][mt][3]);
        }
        float mx = fmaxf(fmaxf(c0, c1), fmaxf(c2, c3));
        // T13 defer-max: if no lane's local max exceeds mI+8, keep stale max
        // (P bounded by 2^8 — safe in bf16); skip max-shfls and O-rescale.
        float mn = mI[sub];
        const bool full = !__all(mx <= mI[sub] + 8.0f);
        if (full) {
          mx = fmaxf(mx, __shfl_xor(mx, 16, 64));
          mx = fmaxf(mx, __shfl_xor(mx, 32, 64));
          mn = fmaxf(mI[sub], mx);
        }
        float t0 = 0.0f, t1 = 0.0f, t2 = 0.0f, t3 = 0.0f;
#pragma unroll
        for (int mt = 0; mt < 8; ++mt) {
          float p0 = exp2f(s[sub][mt][0] - mn);
          float p1 = exp2f(s[sub][mt][1] - mn);
          float p2 = exp2f(s[sub][mt][2] - mn);
          float p3 = exp2f(s[sub][mt][3] - mn);
          s[sub][mt][0] = p0; s[sub][mt][1] = p1;
          s[sub][mt][2] = p2; s[sub][mt][3] = p3;
          t0 += p0; t1 += p1; t2 += p2; t3 += p3;
        }
        float rs = (t0 + t1) + (t2 + t3);
        rs += __shfl_xor(rs, 16, 64);
        rs += __shfl_xor(rs, 32, 64);
        if (full) {
          const float al = exp2f(mI[sub] - mn);
          mI[sub] = mn;
          lI[sub] = lI[sub] * al + rs;
#pragma unroll
          for (int mt = 0; mt < 4; ++mt)
#pragma unroll
            for (int r = 0; r < 4; ++r) o[sub][mt][r] *= al;
        } else {
          lI[sub] += rs;
        }
        // P^T -> Ps (wave-private rows; separate row-sets per sub)
        u16* pr = sub ? pr1 : pr0;
#pragma unroll
        for (int mt = 0; mt < 8; ++mt) {
          uint2 pd;
          pd.x = pkbf(s[sub][mt][0], s[sub][mt][1]);
          pd.y = pkbf(s[sub][mt][2], s[sub][mt][3]);
          *(uint2*)&pr[mt * 16 + lq * 4] = pd;
        }
      }
      if (it + 1 < nt) { VMC(4); } else { VMC(0); }
      BARRIER;          // V(it) visible
      // fused PV: one av read feeds BOTH subtiles.
#pragma unroll
      for (int kk = 0; kk < 4; ++kk) {
        short8 bp0 = *(const short8*)&pr0[kk * 32 + lq * 8];
        short8 bp1 = *(const short8*)&pr1[kk * 32 + lq * 8];
#pragma unroll
        for (int mt = 0; mt < 4; ++mt) {
          int row = mt * 16 + q;
          short8 av = *(const short8*)&Vs[row * 128 + (((kk * 4 + lq) ^ (row & 15)) << 3)];
          o[0][mt] = MFMA16(av, bp0, o[0][mt]);
          o[1][mt] = MFMA16(av, bp1, o[1][mt]);
        }
      }
    }
#pragma unroll
    for (int sub = 0; sub < 2; ++sub) {
      const float inv = 1.0f / lI[sub];
#pragma unroll
      for (int mt = 0; mt < 4; ++mt) {
        uint2 pd;
        pd.x = pkbf(o[sub][mt][0] * inv, o[sub][mt][1] * inv);
        pd.y = pkbf(o[sub][mt][2] * inv, o[sub][mt][3] * inv);
        *(uint2*)&aout[((size_t)(b * 2048 + qcol[sub])) * 1024 + h * 64 + mt * 16 + lq * 4] = pd;
      }
    }
  }
#undef STAGE_K
#undef STAGE_V
#undef BARRIER
}

// ---------------------------------------------------------------------------
// prep_k: fused rmsnorm(ln1) [blocks 0..8191] + weight cvt [blocks 8192..24575].
// ---------------------------------------------------------------------------
__global__ __launch_bounds__(256) void prep_k(
    const float* __restrict__ x, const float* __restrict__ ln1, u16* __restrict__ xout,
    const float* __restrict__ qp, const float* __restrict__ kp,
    const float* __restrict__ vp, const float* __restrict__ op,
    const float* __restrict__ w1, const float* __restrict__ w3,
    const float* __restrict__ w2,
    u16* __restrict__ WQKV, u16* __restrict__ WO,
    u16* __restrict__ W1, u16* __restrict__ W3, u16* __restrict__ W2) {
  __shared__ float red[4];
  const int bid = blockIdx.x;
  const int tid = threadIdx.x;
  if (bid < 8192) {
    const int row = bid;
    const float4 v = ((const float4*)(x + (size_t)row * 1024))[tid];
    float ss = v.x * v.x + v.y * v.y + v.z * v.z + v.w * v.w;
#pragma unroll
    for (int d = 1; d < 64; d <<= 1) ss += __shfl_xor(ss, d, 64);
    if ((tid & 63) == 0) red[tid >> 6] = ss;
    __syncthreads();
    const float sc = rsqrtf((red[0] + red[1] + red[2] + red[3]) * (1.0f / 1024.0f) + 1e-5f);
    const float4 wv = ((const float4*)ln1)[tid];
    uint2 pv;
    pv.x = pkbf(v.x * sc * wv.x, v.y * sc * wv.y);
    pv.y = pkbf(v.z * sc * wv.z, v.w * sc * wv.w);
    *(uint2*)(xout + (size_t)row * 1024 + tid * 4) = pv;
  } else {
    int i = (bid - 8192) * 256 + tid;  // [0, 4194304)
    const float* src;
    u16* dst;
    int off;
    if (i < 1048576) {
      int seg = i >> 18, within = i & 262143;
      src = (seg == 0) ? qp : (seg == 1) ? kp : (seg == 2) ? vp : op;
      dst = (seg == 3) ? WO : WQKV + (size_t)seg * 1048576;
      off = within;
    } else {
      int j = i - 1048576;
      int seg = j >> 20;
      off = j & 1048575;
      src = (seg == 0) ? w1 : (seg == 1) ? w3 : w2;
      dst = (seg == 0) ? W1 : (seg == 1) ? W3 : W2;
    }
    float4 v = ((const float4*)src)[off];
    uint2 pv;
    pv.x = pkbf(v.x, v.y);
    pv.y = pkbf(v.z, v.w);
    *(uint2*)(dst + (size_t)off * 4) = pv;
  }
}

// rmsnorm (ln2) standalone
__global__ __launch_bounds__(256) void rmsnorm_k(
    const float* __restrict__ x, const float* __restrict__ w, u16* __restrict__ out) {
  const int row = blockIdx.x;
  const int tid = threadIdx.x;
  const float4 v = ((const float4*)(x + (size_t)row * 1024))[tid];
  float ss = v.x * v.x + v.y * v.y + v.z * v.z + v.w * v.w;
#pragma unroll
  for (int d = 1; d < 64; d <<= 1) ss += __shfl_xor(ss, d, 64);
  __shared__ float red[4];
  if ((tid & 63) == 0) red[tid >> 6] = ss;
  __syncthreads();
  const float sc = rsqrtf((red[0] + red[1] + red[2] + red[3]) * (1.0f / 1024.0f) + 1e-5f);
  const float4 wv = ((const float4*)w)[tid];
  uint2 pv;
  pv.x = pkbf(v.x * sc * wv.x, v.y * sc * wv.y);
  pv.y = pkbf(v.z * sc * wv.z, v.w * sc * wv.w);
  *(uint2*)(out + (size_t)row * 1024 + tid * 4) = pv;
}

// ---------------------------------------------------------------------------
// rope_tv: fused RoPE [blocks 0..8191] + V-transpose [blocks 8192..10239].
// ---------------------------------------------------------------------------
__global__ __launch_bounds__(256) void rope_tv(
    const u16* __restrict__ qkv, u16* __restrict__ qh, u16* __restrict__ kh,
    const int* __restrict__ pos, u16* __restrict__ vt) {
  __shared__ u16 t[64][65];
  const int bid = blockIdx.x;
  const int tid = threadIdx.x;
  if (bid < 8192) {
    int idx = bid * 256 + tid;  // 8192 rows * 256 groups
    int grp = idx & 255;
    int row = idx >> 8;
    int which = grp >> 7;  // 0=q, 1=k
    int p = grp & 127;
    int s = row & 2047, b = row >> 11;
    int h = p >> 3, gi = p & 7;
    const u16* src = qkv + (size_t)row * 3072 + which * 1024 + h * 64 + gi * 8;
    uint4 in = *(const uint4*)src;
    const u16* e = (const u16*)&in;
    const float fp = (float)pos[s];
    const float scale = which ? 1.0f : 0.18033688011112042f;  // 0.125*log2(e)
    uint4 outv;
    unsigned* ov = (unsigned*)&outv;
#pragma unroll
    for (int j = 0; j < 4; ++j) {
      int i = gi * 4 + j;  // pair index 0..31
      float xe = b2f(e[2 * j]), xo = b2f(e[2 * j + 1]);
      float inv = exp2f(-(float)(2 * i) * (13.287712379549449f / 64.0f));
      float ang = fp * inv;
      float sn, cs;
      __sincosf(ang, &sn, &cs);
      ov[j] = pkbf((xe * cs - xo * sn) * scale, (xe * sn + xo * cs) * scale);
    }
    u16* dst = (which ? kh : qh) + (((size_t)(b * 16 + h)) * 2048 + s) * 64 + gi * 8;
    *(uint4*)dst = outv;
  } else {
    const int bq = bid - 8192;
    const int s0 = (bq & 31) * 64, bh = bq >> 5;
    const int b = bh >> 4, h = bh & 15;
#pragma unroll
    for (int i = 0; i < 16; ++i) {
      int e = i * 256 + tid;
      int sl = e >> 6, d = e & 63;
      t[sl][d] = qkv[((size_t)(b * 2048 + s0 + sl)) * 3072 + 2048 + h * 64 + d];
    }
    __syncthreads();
#pragma unroll
    for (int i = 0; i < 16; ++i) {
      int e = i * 256 + tid;
      int d = e >> 6, sl = e & 63;
      vt[((size_t)(bh * 64 + d)) * 2048 + s0 + sl] = t[sl][d];
    }
  }
}

// ---------------------------------------------------------------------------
extern "C" void kernel_launch(void* const* d_in, const int* in_sizes, int n_in,
                              void* d_out, int out_size, void* d_ws, size_t ws_size,
                              hipStream_t stream) {
  const float* x   = (const float*)d_in[0];
  const int*   pos = (const int*)d_in[1];
  const float* qp  = (const float*)d_in[2];
  const float* kp  = (const float*)d_in[3];
  const float* vp  = (const float*)d_in[4];
  const float* op  = (const float*)d_in[5];
  const float* w1  = (const float*)d_in[6];
  const float* w2  = (const float*)d_in[7];   // dict order: w2 before w3
  const float* w3  = (const float*)d_in[8];
  const float* ln1 = (const float*)d_in[9];
  const float* ln2 = (const float*)d_in[10];
  float* out = (float*)d_out;
  char* ws = (char*)d_ws;
  const size_t MB = 1024 * 1024;

  u16* WQKV = (u16*)(ws + 0 * MB);    // [3072][1024] stacked q,k,v  (6 MB)
  u16* WO   = (u16*)(ws + 6 * MB);
  u16* W1   = (u16*)(ws + 8 * MB);
  u16* W3   = (u16*)(ws + 16 * MB);
  u16* W2   = (u16*)(ws + 24 * MB);
  u16* XLN  = (u16*)(ws + 32 * MB);
  u16* QKV  = (u16*)(ws + 48 * MB);   // [8192][3072]  (48..96 MB)
  u16* QH   = (u16*)(ws + 96 * MB);
  u16* KH   = (u16*)(ws + 112 * MB);
  u16* VT   = (u16*)(ws + 128 * MB);
  u16* ATT  = (u16*)(ws + 48 * MB);   // reuses QKV
  u16* XLN2 = (u16*)(ws + 64 * MB);
  u16* Hbuf = (u16*)(ws + 80 * MB);   // 64 MB (VT dead by then)
  (void)in_sizes; (void)n_in; (void)out_size; (void)ws_size;

  prep_k<<<24576, 256, 0, stream>>>(x, ln1, XLN, qp, kp, vp, op, w1, w3, w2,
                                    WQKV, WO, W1, W3, W2);
  gemm_bt<0><<<dim3(24, 64), 256, 0, stream>>>(XLN, WQKV, QKV, nullptr, nullptr, 8192, 3072, 1024);
  rope_tv<<<10240, 256, 0, stream>>>(QKV, QH, KH, pos, VT);
  attn_k<<<dim3(8, 64), 256, 0, stream>>>(QH, KH, VT, ATT);
  gemm_bt<1><<<dim3(8, 64), 256, 0, stream>>>(ATT, WO, nullptr, out, x, 8192, 1024, 1024);
  rmsnorm_k<<<8192, 256, 0, stream>>>(out, ln2, XLN2);
  ffn_gemm<<<dim3(32, 64), 256, 0, stream>>>(XLN2, W1, W3, Hbuf, 8192, 4096, 1024);
  gemm_bt<1><<<dim3(8, 64), 256, 0, stream>>>(Hbuf, W2, nullptr, out, out, 8192, 1024, 4096);
}